// Round 1
// baseline (11139.660 us; speedup 1.0000x reference)
//
#include <hip/hip_runtime.h>
#include <cmath>

// Problem constants (match reference)
constexpr int kN   = 4096;
constexpr int kIN  = 3000;
constexpr int kLAT = 64;

// accumulator slots in workspace
enum { SL = 0, FEAT, ALN, FXA, FXB, SM1, SM2, SPS, NSLOT };

// ---------------- reduction helpers ----------------
template<bool IS_MAX>
__device__ __forceinline__ float blk_red(float v) {
  __shared__ float buf[4];
  #pragma unroll
  for (int s = 32; s > 0; s >>= 1) {
    float o = __shfl_down(v, s, 64);
    v = IS_MAX ? fmaxf(v, o) : (v + o);
  }
  int lane = threadIdx.x & 63, wv = threadIdx.x >> 6, nw = blockDim.x >> 6;
  __syncthreads();
  if (lane == 0) buf[wv] = v;
  __syncthreads();
  float r = buf[0];
  for (int i = 1; i < nw; i++) r = IS_MAX ? fmaxf(r, buf[i]) : (r + buf[i]);
  return r;
}

__device__ __forceinline__ float wave_red_sum(float v) {
  #pragma unroll
  for (int s = 32; s > 0; s >>= 1) v += __shfl_down(v, s, 64);
  return v;
}

// ---------------- generic tiled fp32 GEMM ----------------
// C[M x Nc] = op(A) @ op(B).  TA: A is K x M (use A^T).  TB: B is Nc x K (use B^T).
// EPI 0: store C = acc*alpha (optionally / coldiv[col])
// EPI 1: atomicAdd into C (split-K accumulation; C must be pre-zeroed)
// EPI 2: reduce sum((X - acc/rowdiv[row])^2) into *slot  (rowdiv optional)
template<int TA, int TB, int EPI>
__global__ __launch_bounds__(256)
void gemm_k(const float* __restrict__ A, const float* __restrict__ B,
            float* __restrict__ C, const float* __restrict__ X,
            const float* __restrict__ rowdiv, const float* __restrict__ coldiv,
            float alpha, float* __restrict__ slot,
            int M, int Nc, int K, int ldA, int ldB, int kchunk)
{
  __shared__ float As[16][68];
  __shared__ float Bs[16][68];
  int tid = threadIdx.x;
  int tx = tid & 15, ty = tid >> 4;
  int row0 = blockIdx.y * 64, col0 = blockIdx.x * 64;
  int kb = blockIdx.z * kchunk;
  int ke = (kb + kchunk < K) ? (kb + kchunk) : K;
  float acc[4][4] = {};

  for (int k0 = kb; k0 < ke; k0 += 16) {
    bool kfull = (k0 + 16 <= ke);
    // ---- A tile -> As[kk][m]
    if (TA == 0) {
      int m = tid >> 2, kk = (tid & 3) << 2;
      const float* ap = A + (size_t)(row0 + m) * ldA + k0 + kk;
      if (kfull) {
        float4 v = *(const float4*)ap;
        As[kk + 0][m] = v.x; As[kk + 1][m] = v.y; As[kk + 2][m] = v.z; As[kk + 3][m] = v.w;
      } else {
        #pragma unroll
        for (int i = 0; i < 4; i++)
          As[kk + i][m] = (k0 + kk + i < ke) ? ap[i] : 0.f;
      }
    } else {
      int kk = tid >> 4, m = (tid & 15) << 2;
      if (k0 + kk < ke) {
        const float* ap = A + (size_t)(k0 + kk) * ldA + row0 + m;
        *(float4*)&As[kk][m] = *(const float4*)ap;
      } else {
        *(float4*)&As[kk][m] = make_float4(0.f, 0.f, 0.f, 0.f);
      }
    }
    // ---- B tile -> Bs[kk][c]
    if (TB == 0) {
      int kk = tid >> 4, c = (tid & 15) << 2;
      const float* bp = B + (size_t)(k0 + kk) * ldB + col0 + c;
      bool kok = (k0 + kk < ke);
      if (kok && (col0 + 64 <= Nc)) {
        *(float4*)&Bs[kk][c] = *(const float4*)bp;
      } else {
        #pragma unroll
        for (int i = 0; i < 4; i++)
          Bs[kk][c + i] = (kok && (col0 + c + i < Nc)) ? bp[i] : 0.f;
      }
    } else {
      int c = tid >> 2, kk = (tid & 3) << 2;
      const float* bp = B + (size_t)(col0 + c) * ldB + k0 + kk;
      bool cok = (col0 + c < Nc);
      if (cok && kfull) {
        float4 v = *(const float4*)bp;
        Bs[kk + 0][c] = v.x; Bs[kk + 1][c] = v.y; Bs[kk + 2][c] = v.z; Bs[kk + 3][c] = v.w;
      } else {
        #pragma unroll
        for (int i = 0; i < 4; i++)
          Bs[kk + i][c] = (cok && (k0 + kk + i < ke)) ? bp[i] : 0.f;
      }
    }
    __syncthreads();
    #pragma unroll
    for (int kk = 0; kk < 16; kk++) {
      float4 a4 = *(const float4*)&As[kk][ty << 2];
      float4 b4 = *(const float4*)&Bs[kk][tx << 2];
      float av[4] = {a4.x, a4.y, a4.z, a4.w};
      float bv[4] = {b4.x, b4.y, b4.z, b4.w};
      #pragma unroll
      for (int i = 0; i < 4; i++)
        #pragma unroll
        for (int j = 0; j < 4; j++)
          acc[i][j] = fmaf(av[i], bv[j], acc[i][j]);
    }
    __syncthreads();
  }

  if (EPI == 0) {
    #pragma unroll
    for (int i = 0; i < 4; i++) {
      int r = row0 + (ty << 2) + i;
      #pragma unroll
      for (int j = 0; j < 4; j++) {
        int c = col0 + (tx << 2) + j;
        if (c < Nc) {
          float v = acc[i][j] * alpha;
          if (coldiv) v /= coldiv[c];
          C[(size_t)r * Nc + c] = v;
        }
      }
    }
  } else if (EPI == 1) {
    #pragma unroll
    for (int i = 0; i < 4; i++) {
      int r = row0 + (ty << 2) + i;
      #pragma unroll
      for (int j = 0; j < 4; j++) {
        int c = col0 + (tx << 2) + j;
        if (c < Nc) atomicAdd(&C[(size_t)r * Nc + c], acc[i][j]);
      }
    }
  } else {
    float part = 0.f;
    #pragma unroll
    for (int i = 0; i < 4; i++) {
      int r = row0 + (ty << 2) + i;
      float rd = rowdiv ? rowdiv[r] : 1.f;
      #pragma unroll
      for (int j = 0; j < 4; j++) {
        int c = col0 + (tx << 2) + j;
        if (c < Nc) {
          float v = acc[i][j];
          if (rowdiv) v /= rd;
          float d = X[(size_t)r * Nc + c] - v;
          part = fmaf(d, d, part);
        }
      }
    }
    float tot = blk_red<false>(part);
    if (tid == 0) atomicAdd(slot, tot);
  }
}

// ---------------- row ops on an N x N matrix (one block per row) ----------------
// mode 0: P = softmax(row)/m1   mode 1: P = P/(m1*rowsum)   mode 2: vec[i] = rowsum
__global__ __launch_bounds__(256)
void rowop_k(float* __restrict__ Pm, float* __restrict__ vec, int mode)
{
  int i = blockIdx.x, tid = threadIdx.x;
  float4* prow = (float4*)(Pm + (size_t)i * kN);
  float4 r[4];
  #pragma unroll
  for (int t = 0; t < 4; t++) r[t] = prow[tid + t * 256];

  if (mode == 0) {
    float m = -3.4e38f;
    #pragma unroll
    for (int t = 0; t < 4; t++)
      m = fmaxf(m, fmaxf(fmaxf(r[t].x, r[t].y), fmaxf(r[t].z, r[t].w)));
    m = blk_red<true>(m);
    float s = 0.f;
    #pragma unroll
    for (int t = 0; t < 4; t++) {
      r[t].x = expf(r[t].x - m); r[t].y = expf(r[t].y - m);
      r[t].z = expf(r[t].z - m); r[t].w = expf(r[t].w - m);
      s += r[t].x + r[t].y + r[t].z + r[t].w;
    }
    s = blk_red<false>(s);
    float f = 1.f / (s * (float)kN);
    #pragma unroll
    for (int t = 0; t < 4; t++) {
      r[t].x *= f; r[t].y *= f; r[t].z *= f; r[t].w *= f;
      prow[tid + t * 256] = r[t];
    }
  } else if (mode == 1) {
    float s = 0.f;
    #pragma unroll
    for (int t = 0; t < 4; t++) s += r[t].x + r[t].y + r[t].z + r[t].w;
    s = blk_red<false>(s);
    float f = 1.f / ((float)kN * s);
    #pragma unroll
    for (int t = 0; t < 4; t++) {
      r[t].x *= f; r[t].y *= f; r[t].z *= f; r[t].w *= f;
      prow[tid + t * 256] = r[t];
    }
  } else {
    float s = 0.f;
    #pragma unroll
    for (int t = 0; t < 4; t++) s += r[t].x + r[t].y + r[t].z + r[t].w;
    s = blk_red<false>(s);
    if (tid == 0) vec[i] = s;
  }
}

// column sums via atomics; cs must be pre-zeroed. grid (kN/256, 32)
__global__ void colsum_k(const float* __restrict__ Pm, float* __restrict__ cs)
{
  int j = blockIdx.x * 256 + threadIdx.x;
  int i0 = blockIdx.y * (kN / 32);
  float s = 0.f;
  for (int i = i0; i < i0 + kN / 32; i++) s += Pm[(size_t)i * kN + j];
  atomicAdd(&cs[j], s);
}

// P[i][j] /= (m2 * cs[j])
__global__ void colscale_k(float* __restrict__ Pm, const float* __restrict__ cs)
{
  size_t t = (size_t)blockIdx.x * blockDim.x + threadIdx.x;
  size_t total = (size_t)kN * kN / 4;
  size_t stride = (size_t)gridDim.x * blockDim.x;
  for (; t < total; t += stride) {
    float4 v = ((float4*)Pm)[t];
    int j = (int)((t * 4) & (kN - 1));
    v.x /= ((float)kN * cs[j + 0]);
    v.y /= ((float)kN * cs[j + 1]);
    v.z /= ((float)kN * cs[j + 2]);
    v.w /= ((float)kN * cs[j + 3]);
    ((float4*)Pm)[t] = v;
  }
}

__global__ void relu_k(const float* __restrict__ in, float* __restrict__ out, int n)
{
  int i = blockIdx.x * blockDim.x + threadIdx.x;
  if (i < n) out[i] = fmaxf(in[i], 0.f);
}

// xea[i,:] = xe[perm[i],:]
__global__ void gather_k(const float* __restrict__ xe, const int* __restrict__ perm,
                         float* __restrict__ xea)
{
  int gid = blockIdx.x * 256 + threadIdx.x;
  int i = gid >> 6, j = gid & 63;
  xea[gid] = xe[(size_t)perm[i] * kLAT + j];
}

// per-row squared L2 norm of an N x 64 matrix (one wave per row)
__global__ void sqnorm_k(const float* __restrict__ H, float* __restrict__ outv)
{
  int gid = blockIdx.x * 256 + threadIdx.x;
  float v = H[gid];
  float p = wave_red_sum(v * v);
  if ((gid & 63) == 0) outv[gid >> 6] = p;
}

// g = sigmoid(normalize(vsum/mask_rowsum))
__global__ void readout_k(const float* __restrict__ vsum, const float* __restrict__ mrs,
                          float* __restrict__ g)
{
  int i = blockIdx.x, j = threadIdx.x;
  float v = vsum[i * 64 + j] / mrs[i];
  float p = v * v;
  #pragma unroll
  for (int s = 1; s < 64; s <<= 1) p += __shfl_xor(p, s, 64);
  float nrm = sqrtf(p);
  v = v / fmaxf(nrm, 1e-12f);
  g[i * 64 + j] = 1.f / (1.f + expf(-v));
}

__device__ __forceinline__ float bce_term(float x, float y) {
  return fmaxf(x, 0.f) - x * y + log1pf(expf(-fabsf(x)));
}

// discriminator rows + BCE accumulation (one wave per row)
__global__ void disc_k(const float* __restrict__ g, const float* __restrict__ ga,
                       const float* __restrict__ hrW, const float* __restrict__ haW,
                       const float* __restrict__ lab, const float* __restrict__ bptr,
                       float* __restrict__ acc)
{
  int i = blockIdx.x, j = threadIdx.x;
  float gj = g[i * 64 + j], gaj = ga[i * 64 + j];
  float hw = hrW[i * 64 + j], haw = haW[i * 64 + j];
  float s1 = hw * gj, s2 = haw * gj, s1a = haw * gaj, s2a = hw * gaj;
  #pragma unroll
  for (int s = 1; s < 64; s <<= 1) {
    s1  += __shfl_xor(s1, s, 64);
    s2  += __shfl_xor(s2, s, 64);
    s1a += __shfl_xor(s1a, s, 64);
    s2a += __shfl_xor(s2a, s, 64);
  }
  if (j == 0) {
    float b = bptr[0];
    float y0 = lab[i * 2 + 0], y1 = lab[i * 2 + 1];
    float t = bce_term(s1 + b, y0) + bce_term(s2 + b, y1)
            + bce_term(s1a + b, y0) + bce_term(s2a + b, y1);
    atomicAdd(&acc[SL], t);
  }
}

// loss_align = sum(P * cdist) and loss_sparsity accumulator in one pass over P
__global__ __launch_bounds__(256)
void alignsp_k(const float* __restrict__ Pm, const float* __restrict__ G,
               const float* __restrict__ sns, const float* __restrict__ snt,
               float* __restrict__ acc)
{
  size_t t = (size_t)blockIdx.x * 256 + threadIdx.x;
  size_t total = (size_t)kN * kN;
  size_t stride = (size_t)gridDim.x * 256;
  float a = 0.f, sp = 0.f;
  for (; t < total; t += stride) {
    float p = Pm[t];
    int i = (int)(t >> 12), j = (int)(t & (kN - 1));
    float d2 = sns[i] + snt[j] - 2.f * G[t];
    a = fmaf(p, sqrtf(fmaxf(d2, 1e-12f)), a);
    sp = fmaf(p, logf(p + 1e-10f), sp);
  }
  a = blk_red<false>(a);
  sp = blk_red<false>(sp);
  if (threadIdx.x == 0) { atomicAdd(&acc[ALN], a); atomicAdd(&acc[SPS], sp); }
}

// combine all accumulators into the 7 outputs; also computes loss_marginal from cs
__global__ __launch_bounds__(256)
void finalize_k(const float* __restrict__ acc, const float* __restrict__ cs,
                float* __restrict__ out)
{
  int tid = threadIdx.x;
  float invm2 = 1.f / (float)kN;
  float t = 0.f;
  for (int j = tid; j < kN; j += 256) {
    float q = cs[j];
    t += q * (logf(q) - invm2);
  }
  t = blk_red<false>(t);
  if (tid == 0) {
    float kld_pq = t * invm2;                       // mean over m2
    float kld_pp = invm2 * (logf(invm2) - invm2);
    out[0] = acc[SL] / (2.f * (float)kN);
    out[1] = acc[FEAT] / ((float)kN * (float)kIN);
    out[2] = acc[ALN];
    out[3] = (acc[FXA] + acc[FXB]) / ((float)kN * (float)kIN);
    out[4] = sqrtf(acc[SM1]) / (float)kN + sqrtf(acc[SM2]) / (float)kN;
    out[5] = (kld_pq - kld_pp) * (float)kN;
    out[6] = -acc[SPS];
  }
}

// ---------------- host-side dispatch ----------------
static void gemm_launch(hipStream_t st, int TA, int TB, int EPI,
                        const float* A, const float* B, float* C, const float* X,
                        const float* rowdiv, const float* coldiv, float alpha, float* slot,
                        int M, int Ncc, int K, int ldA, int ldB, int kchunk)
{
  dim3 grid((Ncc + 63) / 64, M / 64, (K + kchunk - 1) / kchunk);
  dim3 blk(256, 1, 1);
  #define GL(ta, tb, epi) gemm_k<ta, tb, epi><<<grid, blk, 0, st>>>( \
      A, B, C, X, rowdiv, coldiv, alpha, slot, M, Ncc, K, ldA, ldB, kchunk)
  if      (TA == 0 && TB == 0 && EPI == 0) GL(0, 0, 0);
  else if (TA == 0 && TB == 0 && EPI == 1) GL(0, 0, 1);
  else if (TA == 0 && TB == 0 && EPI == 2) GL(0, 0, 2);
  else if (TA == 0 && TB == 1 && EPI == 0) GL(0, 1, 0);
  else if (TA == 1 && TB == 0 && EPI == 2) GL(1, 0, 2);
  #undef GL
}

extern "C" void kernel_launch(void* const* d_in, const int* in_sizes, int n_in,
                              void* d_out, int out_size, void* d_ws, size_t ws_size,
                              hipStream_t stream)
{
  (void)in_sizes; (void)n_in; (void)out_size; (void)ws_size;
  const float* feat  = (const float*)d_in[0];   // (2, N, IN)
  const float* adjs  = (const float*)d_in[1];   // (2, N, N)
  const float* gmask = (const float*)d_in[2];   // (2, N, N)
  const float* labs  = (const float*)d_in[3];   // (2, N, 2)
  const float* dists = (const float*)d_in[4];   // (2, N, N)
  const int*   perms = (const int*)d_in[5];     // (2, N)
  const float* encW  = (const float*)d_in[6];   // (2, IN, 64)
  const float* decW  = (const float*)d_in[7];   // (2, 64, IN)
  const float* MsW   = (const float*)d_in[8];   // (1, 64, 64)
  const float* discW = (const float*)d_in[9];   // (64, 64)
  const float* discb = (const float*)d_in[10];  // (1,)
  float* out = (float*)d_out;
  float* w = (float*)d_ws;

  const size_t SZNN = (size_t)kN * kN;
  const size_t SZNL = (size_t)kN * kLAT;
  float* P   = w;
  float* T   = P + SZNN;
  float* h0  = T + SZNN;
  float* h1  = h0 + SZNL;
  float* xe  = h1 + SZNL;   // reused as srcM in phase B
  float* xea = xe + SZNL;   // reused as tgtM in phase B
  float* ha  = xea + SZNL;
  float* ah  = ha + SZNL;
  float* hr  = ah + SZNL;
  float* har = hr + SZNL;
  float* vs  = har + SZNL;
  float* vsa = vs + SZNL;
  float* g   = vsa + SZNL;
  float* ga  = g + SZNL;
  float* hrW = ga + SZNL;
  float* haW = hrW + SZNL;
  float* sns = haW + SZNL;
  float* snt = sns + kN;
  float* rs  = snt + kN;
  float* cs  = rs + kN;
  float* mrs = cs + kN;
  float* acc = mrs + kN;

  hipMemsetAsync(acc, 0, NSLOT * sizeof(float), stream);

  // ---------------- per-slice encode/decode/discriminator losses ----------------
  for (int k = 0; k < 2; k++) {
    const float* x    = feat  + (size_t)k * kN * kIN;
    const float* adj  = adjs  + (size_t)k * SZNN;
    const float* msk  = gmask + (size_t)k * SZNN;
    const float* lab  = labs  + (size_t)k * kN * 2;
    const int*   perm = perms + (size_t)k * kN;
    const float* eW   = encW  + (size_t)k * kIN * kLAT;
    const float* dW   = decW  + (size_t)k * kLAT * kIN;
    float* hk = (k == 0) ? h0 : h1;

    // xe = x @ encW      (split-K atomic)
    hipMemsetAsync(xe, 0, SZNL * sizeof(float), stream);
    gemm_launch(stream, 0, 0, 1, x, eW, xe, nullptr, nullptr, nullptr, 1.f, nullptr,
                kN, kLAT, kIN, kIN, kLAT, 384);
    // xea = xe[perm]  (x_a @ encW == (x @ encW)[perm])
    gather_k<<<(int)(SZNL / 256), 256, 0, stream>>>(xe, perm, xea);
    // h = adj @ xe
    hipMemsetAsync(hk, 0, SZNL * sizeof(float), stream);
    gemm_launch(stream, 0, 0, 1, adj, xe, hk, nullptr, nullptr, nullptr, 1.f, nullptr,
                kN, kLAT, kN, kN, kLAT, 512);
    // h_a = adj @ xea
    hipMemsetAsync(ha, 0, SZNL * sizeof(float), stream);
    gemm_launch(stream, 0, 0, 1, adj, xea, ha, nullptr, nullptr, nullptr, 1.f, nullptr,
                kN, kLAT, kN, kN, kLAT, 512);
    // ah = adj @ h   (reassociation: out = adj@(h@dec) = (adj@h)@dec)
    hipMemsetAsync(ah, 0, SZNL * sizeof(float), stream);
    gemm_launch(stream, 0, 0, 1, adj, hk, ah, nullptr, nullptr, nullptr, 1.f, nullptr,
                kN, kLAT, kN, kN, kLAT, 512);
    // loss_feat += sum((x - ah@decW)^2)   (fused epilogue)
    gemm_launch(stream, 0, 0, 2, ah, dW, nullptr, x, nullptr, nullptr, 1.f, &acc[FEAT],
                kN, kIN, kLAT, kLAT, kIN, kLAT);
    // relu
    relu_k<<<(int)(SZNL / 256), 256, 0, stream>>>(hk, hr, (int)SZNL);
    relu_k<<<(int)(SZNL / 256), 256, 0, stream>>>(ha, har, (int)SZNL);
    // mask rowsums
    rowop_k<<<kN, 256, 0, stream>>>((float*)msk, mrs, 2);
    // vsum = mask @ relu(h)
    hipMemsetAsync(vs, 0, SZNL * sizeof(float), stream);
    gemm_launch(stream, 0, 0, 1, msk, hr, vs, nullptr, nullptr, nullptr, 1.f, nullptr,
                kN, kLAT, kN, kN, kLAT, 512);
    hipMemsetAsync(vsa, 0, SZNL * sizeof(float), stream);
    gemm_launch(stream, 0, 0, 1, msk, har, vsa, nullptr, nullptr, nullptr, 1.f, nullptr,
                kN, kLAT, kN, kN, kLAT, 512);
    // g = sigmoid(normalize(vsum/mrs))
    readout_k<<<kN, 64, 0, stream>>>(vs, mrs, g);
    readout_k<<<kN, 64, 0, stream>>>(vsa, mrs, ga);
    // hrW = relu(h) @ discW ; haW = relu(h_a) @ discW
    gemm_launch(stream, 0, 0, 0, hr, discW, hrW, nullptr, nullptr, nullptr, 1.f, nullptr,
                kN, kLAT, kLAT, kLAT, kLAT, kLAT);
    gemm_launch(stream, 0, 0, 0, har, discW, haW, nullptr, nullptr, nullptr, 1.f, nullptr,
                kN, kLAT, kLAT, kLAT, kLAT, kLAT);
    // BCE
    disc_k<<<kN, 64, 0, stream>>>(g, ga, hrW, haW, lab, discb, acc);
  }

  // ---------------- alignment losses (k=1) ----------------
  const float* f0 = feat;
  const float* f1 = feat + (size_t)kN * kIN;
  const float* D0 = dists;
  const float* D1 = dists + SZNN;

  // srcM = h0 @ M, tgtM = h1 @ M
  gemm_launch(stream, 0, 0, 0, h0, MsW, xe, nullptr, nullptr, nullptr, 1.f, nullptr,
              kN, kLAT, kLAT, kLAT, kLAT, kLAT);
  gemm_launch(stream, 0, 0, 0, h1, MsW, xea, nullptr, nullptr, nullptr, 1.f, nullptr,
              kN, kLAT, kLAT, kLAT, kLAT, kLAT);
  // C = srcM @ tgtM^T / 8
  gemm_launch(stream, 0, 1, 0, xe, xea, P, nullptr, nullptr, nullptr, 0.125f, nullptr,
              kN, kN, kLAT, kLAT, kLAT, kLAT);
  // P = softmax(C,1)/m1
  rowop_k<<<kN, 256, 0, stream>>>(P, nullptr, 0);
  // Sinkhorn x3
  for (int it = 0; it < 3; it++) {
    rowop_k<<<kN, 256, 0, stream>>>(P, nullptr, 1);
    hipMemsetAsync(cs, 0, kN * sizeof(float), stream);
    colsum_k<<<dim3(kN / 256, 32), 256, 0, stream>>>(P, cs);
    colscale_k<<<2048, 256, 0, stream>>>(P, cs);
  }
  // final marginals
  rowop_k<<<kN, 256, 0, stream>>>(P, rs, 2);
  hipMemsetAsync(cs, 0, kN * sizeof(float), stream);
  colsum_k<<<dim3(kN / 256, 32), 256, 0, stream>>>(P, cs);
  // squared norms of h0/h1 rows
  sqnorm_k<<<(int)(SZNL / 256), 256, 0, stream>>>(h0, sns);
  sqnorm_k<<<(int)(SZNL / 256), 256, 0, stream>>>(h1, snt);
  // G = h0 @ h1^T  (for cdist)
  gemm_launch(stream, 0, 1, 0, h0, h1, T, nullptr, nullptr, nullptr, 1.f, nullptr,
              kN, kN, kLAT, kLAT, kLAT, kLAT);
  // loss_align + sparsity accumulators
  alignsp_k<<<4096, 256, 0, stream>>>(P, T, sns, snt, acc);
  // loss_align_fix: sum((f0 - (P@f1)/rs)^2), sum((f1 - (P^T@f0)/cs)^2)
  gemm_launch(stream, 0, 0, 2, P, f1, nullptr, f0, rs, nullptr, 1.f, &acc[FXA],
              kN, kIN, kN, kN, kIN, kN);
  gemm_launch(stream, 1, 0, 2, P, f0, nullptr, f1, cs, nullptr, 1.f, &acc[FXB],
              kN, kIN, kN, kN, kIN, kN);
  // loss_maintain part 1: T = (D1 @ P^T)/rs[col] ; S1 = sum((D0 - (P@T)/rs)^2)
  gemm_launch(stream, 0, 1, 0, D1, P, T, nullptr, nullptr, rs, 1.f, nullptr,
              kN, kN, kN, kN, kN, kN);
  gemm_launch(stream, 0, 0, 2, P, T, nullptr, D0, rs, nullptr, 1.f, &acc[SM1],
              kN, kN, kN, kN, kN, kN);
  // loss_maintain part 2: T = (D0 @ P)/cs[col] ; S2 = sum((D1 - (P^T@T)/cs)^2)
  gemm_launch(stream, 0, 0, 0, D0, P, T, nullptr, nullptr, cs, 1.f, nullptr,
              kN, kN, kN, kN, kN, kN);
  gemm_launch(stream, 1, 0, 2, P, T, nullptr, D1, cs, nullptr, 1.f, &acc[SM2],
              kN, kN, kN, kN, kN, kN);
  // finalize all 7 losses
  finalize_k<<<1, 256, 0, stream>>>(acc, cs, out);
}

// Round 2
// 4586.662 us; speedup vs baseline: 2.4287x; 2.4287x over previous
//
#include <hip/hip_runtime.h>
#include <cmath>

// Problem constants (match reference)
constexpr int kN   = 4096;
constexpr int kIN  = 3000;
constexpr int kLAT = 64;

// accumulator slots in workspace
enum { SL = 0, FEAT, ALN, FXA, FXB, SM1, SM2, SPS, NSLOT };

typedef __bf16 bf16x8 __attribute__((ext_vector_type(8)));
typedef float f32x4 __attribute__((ext_vector_type(4)));
typedef unsigned short u16x8 __attribute__((ext_vector_type(8)));
typedef unsigned short u16x4 __attribute__((ext_vector_type(4)));

// ---------------- reduction helpers ----------------
template<bool IS_MAX>
__device__ __forceinline__ float blk_red(float v) {
  __shared__ float buf[4];
  #pragma unroll
  for (int s = 32; s > 0; s >>= 1) {
    float o = __shfl_down(v, s, 64);
    v = IS_MAX ? fmaxf(v, o) : (v + o);
  }
  int lane = threadIdx.x & 63, wv = threadIdx.x >> 6, nw = blockDim.x >> 6;
  __syncthreads();
  if (lane == 0) buf[wv] = v;
  __syncthreads();
  float r = buf[0];
  for (int i = 1; i < nw; i++) r = IS_MAX ? fmaxf(r, buf[i]) : (r + buf[i]);
  return r;
}

__device__ __forceinline__ float wave_red_sum(float v) {
  #pragma unroll
  for (int s = 32; s > 0; s >>= 1) v += __shfl_down(v, s, 64);
  return v;
}

// fp32 -> bf16 round-to-nearest-even (finite inputs)
__device__ __forceinline__ unsigned short f2bf(float f) {
  unsigned u = __builtin_bit_cast(unsigned, f);
  u += 0x7fffu + ((u >> 16) & 1u);
  return (unsigned short)(u >> 16);
}

// ================== bf16 MFMA GEMM (128x128 tile, BK=32) ==================
// LDS tiles are [128 rows][32 k] bf16 with row pitch 40 elems (80 B) to
// spread ds_read_b128 frag reads across banks (stride 80B -> 2-way, free).
constexpr int LDT = 40;

// stage, no transpose: dst[r][k] = S[(r0+r)*ld + k0+k]; zero rows >= rmax
__device__ __forceinline__ void stage_nt(unsigned short* dst, const float* __restrict__ S,
                                         int r0, int k0, int ld, int rmax, int t)
{
  int r = t >> 1, ks = (t & 1) << 4;
  u16x8 p0, p1;
  if (r0 + r < rmax) {
    const float* sp = S + (size_t)(r0 + r) * ld + k0 + ks;
    float4 a = *(const float4*)(sp);
    float4 b = *(const float4*)(sp + 4);
    float4 c = *(const float4*)(sp + 8);
    float4 d = *(const float4*)(sp + 12);
    p0[0] = f2bf(a.x); p0[1] = f2bf(a.y); p0[2] = f2bf(a.z); p0[3] = f2bf(a.w);
    p0[4] = f2bf(b.x); p0[5] = f2bf(b.y); p0[6] = f2bf(b.z); p0[7] = f2bf(b.w);
    p1[0] = f2bf(c.x); p1[1] = f2bf(c.y); p1[2] = f2bf(c.z); p1[3] = f2bf(c.w);
    p1[4] = f2bf(d.x); p1[5] = f2bf(d.y); p1[6] = f2bf(d.z); p1[7] = f2bf(d.w);
  } else {
    p0 = (u16x8)0; p1 = (u16x8)0;
  }
  *(u16x8*)&dst[r * LDT + ks] = p0;
  *(u16x8*)&dst[r * LDT + ks + 8] = p1;
}

// stage with transpose: dst[c][k] = S[(k0+k)*ld + c0+c]; zero cols >= cmax
__device__ __forceinline__ void stage_tr(unsigned short* dst, const float* __restrict__ S,
                                         int c0, int k0, int ld, int cmax, int t)
{
  int tk = (t & 7) << 2, tc = (t >> 3) << 2;
  bool ok = (c0 + tc < cmax);
  float4 v[4];
  #pragma unroll
  for (int i = 0; i < 4; i++) {
    if (ok) v[i] = *(const float4*)(S + (size_t)(k0 + tk + i) * ld + c0 + tc);
    else v[i] = make_float4(0.f, 0.f, 0.f, 0.f);
  }
  #pragma unroll
  for (int j = 0; j < 4; j++) {
    u16x4 w;
    w[0] = f2bf(((const float*)&v[0])[j]);
    w[1] = f2bf(((const float*)&v[1])[j]);
    w[2] = f2bf(((const float*)&v[2])[j]);
    w[3] = f2bf(((const float*)&v[3])[j]);
    *(u16x4*)&dst[(tc + j) * LDT + tk] = w;
  }
}

// M fixed = 4096 (gridDim.y = 32). TRA: A given as K x M (use A^T).
// TRB: B given as N x K (use B^T; i.e. logical B[k][c] = src[c][k]).
// EPI 0: C[r*ldCX+c] = acc / coldiv[c]      (fp32 store)
// EPI 2: slot += wgt * sum((X - acc/rowdiv[r])^2); sym=1 -> upper-tri blocks only, x2 off-diag
template<int TRA, int TRB, int EPI>
__global__ __launch_bounds__(256)
void gemm_mfma_k(const float* __restrict__ A, const float* __restrict__ B,
                 float* __restrict__ C, const float* __restrict__ X,
                 const float* __restrict__ rowdiv, const float* __restrict__ coldiv,
                 float* __restrict__ slot, int Nc, int K,
                 int ldA, int ldB, int ldCX, int sym)
{
  __shared__ unsigned short As[128 * LDT];
  __shared__ unsigned short Bs[128 * LDT];
  const int t = threadIdx.x;
  const int row0 = blockIdx.y * 128, col0 = blockIdx.x * 128;
  if (EPI == 2 && sym && col0 < row0) return;

  f32x4 acc[4][4];
  #pragma unroll
  for (int i = 0; i < 4; i++)
    #pragma unroll
    for (int j = 0; j < 4; j++) acc[i][j] = (f32x4){0.f, 0.f, 0.f, 0.f};

  const int l = t & 63, wv = t >> 6;
  const int wr = wv >> 1, wc = wv & 1;
  const int lr = l & 15, lk = (l >> 4) << 3;

  for (int k0 = 0; k0 < K; k0 += 32) {
    if (TRA == 0) stage_nt(As, A, row0, k0, ldA, 1 << 30, t);
    else          stage_tr(As, A, row0, k0, ldA, 1 << 30, t);
    if (TRB == 0) stage_tr(Bs, B, col0, k0, ldB, Nc, t);
    else          stage_nt(Bs, B, col0, k0, ldB, Nc, t);
    __syncthreads();
    u16x8 af[4], bfr[4];
    #pragma unroll
    for (int mi = 0; mi < 4; mi++)
      af[mi] = *(const u16x8*)&As[(wr * 64 + mi * 16 + lr) * LDT + lk];
    #pragma unroll
    for (int ni = 0; ni < 4; ni++)
      bfr[ni] = *(const u16x8*)&Bs[(wc * 64 + ni * 16 + lr) * LDT + lk];
    #pragma unroll
    for (int mi = 0; mi < 4; mi++)
      #pragma unroll
      for (int ni = 0; ni < 4; ni++)
        acc[mi][ni] = __builtin_amdgcn_mfma_f32_16x16x32_bf16(
            __builtin_bit_cast(bf16x8, af[mi]),
            __builtin_bit_cast(bf16x8, bfr[ni]),
            acc[mi][ni], 0, 0, 0);
    __syncthreads();
  }

  // C/D fragment mapping: col = lane&15, row = (lane>>4)*4 + reg
  const int lcol = l & 15, lrow = (l >> 4) << 2;
  if (EPI == 0) {
    #pragma unroll
    for (int mi = 0; mi < 4; mi++) {
      int rr = row0 + wr * 64 + mi * 16 + lrow;
      #pragma unroll
      for (int ni = 0; ni < 4; ni++) {
        int cc = col0 + wc * 64 + ni * 16 + lcol;
        if (cc < Nc) {
          float cd = coldiv ? coldiv[cc] : 1.f;
          #pragma unroll
          for (int r = 0; r < 4; r++)
            C[(size_t)(rr + r) * ldCX + cc] = acc[mi][ni][r] / cd;
        }
      }
    }
  } else {
    float part = 0.f;
    #pragma unroll
    for (int mi = 0; mi < 4; mi++) {
      int rr = row0 + wr * 64 + mi * 16 + lrow;
      #pragma unroll
      for (int ni = 0; ni < 4; ni++) {
        int cc = col0 + wc * 64 + ni * 16 + lcol;
        if (cc < Nc) {
          #pragma unroll
          for (int r = 0; r < 4; r++) {
            float v = acc[mi][ni][r];
            if (rowdiv) v /= rowdiv[rr + r];
            float d = X[(size_t)(rr + r) * ldCX + cc] - v;
            part = fmaf(d, d, part);
          }
        }
      }
    }
    part = blk_red<false>(part);
    if (t == 0) {
      float wgt = (sym && col0 > row0) ? 2.f : 1.f;
      atomicAdd(slot, part * wgt);
    }
  }
}

// ---------------- generic tiled fp32 GEMM (kept for skinny / small-K work) --------
template<int TA, int TB, int EPI>
__global__ __launch_bounds__(256)
void gemm_k(const float* __restrict__ A, const float* __restrict__ B,
            float* __restrict__ C, const float* __restrict__ X,
            const float* __restrict__ rowdiv, const float* __restrict__ coldiv,
            float alpha, float* __restrict__ slot,
            int M, int Nc, int K, int ldA, int ldB, int kchunk)
{
  __shared__ float As[16][68];
  __shared__ float Bs[16][68];
  int tid = threadIdx.x;
  int tx = tid & 15, ty = tid >> 4;
  int row0 = blockIdx.y * 64, col0 = blockIdx.x * 64;
  int kb = blockIdx.z * kchunk;
  int ke = (kb + kchunk < K) ? (kb + kchunk) : K;
  float acc[4][4] = {};

  for (int k0 = kb; k0 < ke; k0 += 16) {
    bool kfull = (k0 + 16 <= ke);
    if (TA == 0) {
      int m = tid >> 2, kk = (tid & 3) << 2;
      const float* ap = A + (size_t)(row0 + m) * ldA + k0 + kk;
      if (kfull) {
        float4 v = *(const float4*)ap;
        As[kk + 0][m] = v.x; As[kk + 1][m] = v.y; As[kk + 2][m] = v.z; As[kk + 3][m] = v.w;
      } else {
        #pragma unroll
        for (int i = 0; i < 4; i++)
          As[kk + i][m] = (k0 + kk + i < ke) ? ap[i] : 0.f;
      }
    } else {
      int kk = tid >> 4, m = (tid & 15) << 2;
      if (k0 + kk < ke) {
        const float* ap = A + (size_t)(k0 + kk) * ldA + row0 + m;
        *(float4*)&As[kk][m] = *(const float4*)ap;
      } else {
        *(float4*)&As[kk][m] = make_float4(0.f, 0.f, 0.f, 0.f);
      }
    }
    if (TB == 0) {
      int kk = tid >> 4, c = (tid & 15) << 2;
      const float* bp = B + (size_t)(k0 + kk) * ldB + col0 + c;
      bool kok = (k0 + kk < ke);
      if (kok && (col0 + 64 <= Nc)) {
        *(float4*)&Bs[kk][c] = *(const float4*)bp;
      } else {
        #pragma unroll
        for (int i = 0; i < 4; i++)
          Bs[kk][c + i] = (kok && (col0 + c + i < Nc)) ? bp[i] : 0.f;
      }
    } else {
      int c = tid >> 2, kk = (tid & 3) << 2;
      const float* bp = B + (size_t)(col0 + c) * ldB + k0 + kk;
      bool cok = (col0 + c < Nc);
      if (cok && kfull) {
        float4 v = *(const float4*)bp;
        Bs[kk + 0][c] = v.x; Bs[kk + 1][c] = v.y; Bs[kk + 2][c] = v.z; Bs[kk + 3][c] = v.w;
      } else {
        #pragma unroll
        for (int i = 0; i < 4; i++)
          Bs[kk + i][c] = (cok && (k0 + kk + i < ke)) ? bp[i] : 0.f;
      }
    }
    __syncthreads();
    #pragma unroll
    for (int kk = 0; kk < 16; kk++) {
      float4 a4 = *(const float4*)&As[kk][ty << 2];
      float4 b4 = *(const float4*)&Bs[kk][tx << 2];
      float av[4] = {a4.x, a4.y, a4.z, a4.w};
      float bv[4] = {b4.x, b4.y, b4.z, b4.w};
      #pragma unroll
      for (int i = 0; i < 4; i++)
        #pragma unroll
        for (int j = 0; j < 4; j++)
          acc[i][j] = fmaf(av[i], bv[j], acc[i][j]);
    }
    __syncthreads();
  }

  if (EPI == 0) {
    #pragma unroll
    for (int i = 0; i < 4; i++) {
      int r = row0 + (ty << 2) + i;
      #pragma unroll
      for (int j = 0; j < 4; j++) {
        int c = col0 + (tx << 2) + j;
        if (c < Nc) {
          float v = acc[i][j] * alpha;
          if (coldiv) v /= coldiv[c];
          C[(size_t)r * Nc + c] = v;
        }
      }
    }
  } else if (EPI == 1) {
    #pragma unroll
    for (int i = 0; i < 4; i++) {
      int r = row0 + (ty << 2) + i;
      #pragma unroll
      for (int j = 0; j < 4; j++) {
        int c = col0 + (tx << 2) + j;
        if (c < Nc) atomicAdd(&C[(size_t)r * Nc + c], acc[i][j]);
      }
    }
  } else {
    float part = 0.f;
    #pragma unroll
    for (int i = 0; i < 4; i++) {
      int r = row0 + (ty << 2) + i;
      float rd = rowdiv ? rowdiv[r] : 1.f;
      #pragma unroll
      for (int j = 0; j < 4; j++) {
        int c = col0 + (tx << 2) + j;
        if (c < Nc) {
          float v = acc[i][j];
          if (rowdiv) v /= rd;
          float d = X[(size_t)r * Nc + c] - v;
          part = fmaf(d, d, part);
        }
      }
    }
    float tot = blk_red<false>(part);
    if (tid == 0) atomicAdd(slot, tot);
  }
}

// ---------------- row ops on an N x N matrix (one block per row) ----------------
__global__ __launch_bounds__(256)
void rowop_k(float* __restrict__ Pm, float* __restrict__ vec, int mode)
{
  int i = blockIdx.x, tid = threadIdx.x;
  float4* prow = (float4*)(Pm + (size_t)i * kN);
  float4 r[4];
  #pragma unroll
  for (int t = 0; t < 4; t++) r[t] = prow[tid + t * 256];

  if (mode == 0) {
    float m = -3.4e38f;
    #pragma unroll
    for (int t = 0; t < 4; t++)
      m = fmaxf(m, fmaxf(fmaxf(r[t].x, r[t].y), fmaxf(r[t].z, r[t].w)));
    m = blk_red<true>(m);
    float s = 0.f;
    #pragma unroll
    for (int t = 0; t < 4; t++) {
      r[t].x = expf(r[t].x - m); r[t].y = expf(r[t].y - m);
      r[t].z = expf(r[t].z - m); r[t].w = expf(r[t].w - m);
      s += r[t].x + r[t].y + r[t].z + r[t].w;
    }
    s = blk_red<false>(s);
    float f = 1.f / (s * (float)kN);
    #pragma unroll
    for (int t = 0; t < 4; t++) {
      r[t].x *= f; r[t].y *= f; r[t].z *= f; r[t].w *= f;
      prow[tid + t * 256] = r[t];
    }
  } else if (mode == 1) {
    float s = 0.f;
    #pragma unroll
    for (int t = 0; t < 4; t++) s += r[t].x + r[t].y + r[t].z + r[t].w;
    s = blk_red<false>(s);
    float f = 1.f / ((float)kN * s);
    #pragma unroll
    for (int t = 0; t < 4; t++) {
      r[t].x *= f; r[t].y *= f; r[t].z *= f; r[t].w *= f;
      prow[tid + t * 256] = r[t];
    }
  } else {
    float s = 0.f;
    #pragma unroll
    for (int t = 0; t < 4; t++) s += r[t].x + r[t].y + r[t].z + r[t].w;
    s = blk_red<false>(s);
    if (tid == 0) vec[i] = s;
  }
}

__global__ void colsum_k(const float* __restrict__ Pm, float* __restrict__ cs)
{
  int j = blockIdx.x * 256 + threadIdx.x;
  int i0 = blockIdx.y * (kN / 32);
  float s = 0.f;
  for (int i = i0; i < i0 + kN / 32; i++) s += Pm[(size_t)i * kN + j];
  atomicAdd(&cs[j], s);
}

__global__ void colscale_k(float* __restrict__ Pm, const float* __restrict__ cs)
{
  size_t t = (size_t)blockIdx.x * blockDim.x + threadIdx.x;
  size_t total = (size_t)kN * kN / 4;
  size_t stride = (size_t)gridDim.x * blockDim.x;
  for (; t < total; t += stride) {
    float4 v = ((float4*)Pm)[t];
    int j = (int)((t * 4) & (kN - 1));
    v.x /= ((float)kN * cs[j + 0]);
    v.y /= ((float)kN * cs[j + 1]);
    v.z /= ((float)kN * cs[j + 2]);
    v.w /= ((float)kN * cs[j + 3]);
    ((float4*)Pm)[t] = v;
  }
}

__global__ void relu_k(const float* __restrict__ in, float* __restrict__ out, int n)
{
  int i = blockIdx.x * blockDim.x + threadIdx.x;
  if (i < n) out[i] = fmaxf(in[i], 0.f);
}

__global__ void gather_k(const float* __restrict__ xe, const int* __restrict__ perm,
                         float* __restrict__ xea)
{
  int gid = blockIdx.x * 256 + threadIdx.x;
  int i = gid >> 6, j = gid & 63;
  xea[gid] = xe[(size_t)perm[i] * kLAT + j];
}

__global__ void sqnorm_k(const float* __restrict__ H, float* __restrict__ outv)
{
  int gid = blockIdx.x * 256 + threadIdx.x;
  float v = H[gid];
  float p = wave_red_sum(v * v);
  if ((gid & 63) == 0) outv[gid >> 6] = p;
}

__global__ void readout_k(const float* __restrict__ vsum, const float* __restrict__ mrs,
                          float* __restrict__ g)
{
  int i = blockIdx.x, j = threadIdx.x;
  float v = vsum[i * 64 + j] / mrs[i];
  float p = v * v;
  #pragma unroll
  for (int s = 1; s < 64; s <<= 1) p += __shfl_xor(p, s, 64);
  float nrm = sqrtf(p);
  v = v / fmaxf(nrm, 1e-12f);
  g[i * 64 + j] = 1.f / (1.f + expf(-v));
}

__device__ __forceinline__ float bce_term(float x, float y) {
  return fmaxf(x, 0.f) - x * y + log1pf(expf(-fabsf(x)));
}

__global__ void disc_k(const float* __restrict__ g, const float* __restrict__ ga,
                       const float* __restrict__ hrW, const float* __restrict__ haW,
                       const float* __restrict__ lab, const float* __restrict__ bptr,
                       float* __restrict__ acc)
{
  int i = blockIdx.x, j = threadIdx.x;
  float gj = g[i * 64 + j], gaj = ga[i * 64 + j];
  float hw = hrW[i * 64 + j], haw = haW[i * 64 + j];
  float s1 = hw * gj, s2 = haw * gj, s1a = haw * gaj, s2a = hw * gaj;
  #pragma unroll
  for (int s = 1; s < 64; s <<= 1) {
    s1  += __shfl_xor(s1, s, 64);
    s2  += __shfl_xor(s2, s, 64);
    s1a += __shfl_xor(s1a, s, 64);
    s2a += __shfl_xor(s2a, s, 64);
  }
  if (j == 0) {
    float b = bptr[0];
    float y0 = lab[i * 2 + 0], y1 = lab[i * 2 + 1];
    float t = bce_term(s1 + b, y0) + bce_term(s2 + b, y1)
            + bce_term(s1a + b, y0) + bce_term(s2a + b, y1);
    atomicAdd(&acc[SL], t);
  }
}

__global__ __launch_bounds__(256)
void alignsp_k(const float* __restrict__ Pm, const float* __restrict__ G,
               const float* __restrict__ sns, const float* __restrict__ snt,
               float* __restrict__ acc)
{
  size_t t = (size_t)blockIdx.x * 256 + threadIdx.x;
  size_t total = (size_t)kN * kN;
  size_t stride = (size_t)gridDim.x * 256;
  float a = 0.f, sp = 0.f;
  for (; t < total; t += stride) {
    float p = Pm[t];
    int i = (int)(t >> 12), j = (int)(t & (kN - 1));
    float d2 = sns[i] + snt[j] - 2.f * G[t];
    a = fmaf(p, sqrtf(fmaxf(d2, 1e-12f)), a);
    sp = fmaf(p, logf(p + 1e-10f), sp);
  }
  a = blk_red<false>(a);
  sp = blk_red<false>(sp);
  if (threadIdx.x == 0) { atomicAdd(&acc[ALN], a); atomicAdd(&acc[SPS], sp); }
}

__global__ __launch_bounds__(256)
void finalize_k(const float* __restrict__ acc, const float* __restrict__ cs,
                float* __restrict__ out)
{
  int tid = threadIdx.x;
  float invm2 = 1.f / (float)kN;
  float t = 0.f;
  for (int j = tid; j < kN; j += 256) {
    float q = cs[j];
    t += q * (logf(q) - invm2);
  }
  t = blk_red<false>(t);
  if (tid == 0) {
    float kld_pq = t * invm2;
    float kld_pp = invm2 * (logf(invm2) - invm2);
    out[0] = acc[SL] / (2.f * (float)kN);
    out[1] = acc[FEAT] / ((float)kN * (float)kIN);
    out[2] = acc[ALN];
    out[3] = (acc[FXA] + acc[FXB]) / ((float)kN * (float)kIN);
    out[4] = sqrtf(acc[SM1]) / (float)kN + sqrtf(acc[SM2]) / (float)kN;
    out[5] = (kld_pq - kld_pp) * (float)kN;
    out[6] = -acc[SPS];
  }
}

// ---------------- host-side dispatch ----------------
static void gemm_launch(hipStream_t st, int TA, int TB, int EPI,
                        const float* A, const float* B, float* C, const float* X,
                        const float* rowdiv, const float* coldiv, float alpha, float* slot,
                        int M, int Ncc, int K, int ldA, int ldB, int kchunk)
{
  dim3 grid((Ncc + 63) / 64, M / 64, (K + kchunk - 1) / kchunk);
  dim3 blk(256, 1, 1);
  #define GL(ta, tb, epi) gemm_k<ta, tb, epi><<<grid, blk, 0, st>>>( \
      A, B, C, X, rowdiv, coldiv, alpha, slot, M, Ncc, K, ldA, ldB, kchunk)
  if      (TA == 0 && TB == 0 && EPI == 0) GL(0, 0, 0);
  else if (TA == 0 && TB == 0 && EPI == 1) GL(0, 0, 1);
  else if (TA == 0 && TB == 0 && EPI == 2) GL(0, 0, 2);
  else if (TA == 0 && TB == 1 && EPI == 0) GL(0, 1, 0);
  #undef GL
}

static void mfma_launch(hipStream_t st, int TRA, int TRB, int EPI,
                        const float* A, const float* B, float* C, const float* X,
                        const float* rowdiv, const float* coldiv, float* slot,
                        int Nc, int K, int ldA, int ldB, int ldCX, int sym)
{
  dim3 grid((Nc + 127) / 128, 32);
  dim3 blk(256, 1, 1);
  #define ML(ta, tb, epi) gemm_mfma_k<ta, tb, epi><<<grid, blk, 0, st>>>( \
      A, B, C, X, rowdiv, coldiv, slot, Nc, K, ldA, ldB, ldCX, sym)
  if      (TRA == 0 && TRB == 0 && EPI == 2) ML(0, 0, 2);
  else if (TRA == 1 && TRB == 0 && EPI == 2) ML(1, 0, 2);
  else if (TRA == 0 && TRB == 1 && EPI == 0) ML(0, 1, 0);
  else if (TRA == 0 && TRB == 0 && EPI == 0) ML(0, 0, 0);
  #undef ML
}

extern "C" void kernel_launch(void* const* d_in, const int* in_sizes, int n_in,
                              void* d_out, int out_size, void* d_ws, size_t ws_size,
                              hipStream_t stream)
{
  (void)in_sizes; (void)n_in; (void)out_size; (void)ws_size;
  const float* feat  = (const float*)d_in[0];
  const float* adjs  = (const float*)d_in[1];
  const float* gmask = (const float*)d_in[2];
  const float* labs  = (const float*)d_in[3];
  const float* dists = (const float*)d_in[4];
  const int*   perms = (const int*)d_in[5];
  const float* encW  = (const float*)d_in[6];
  const float* decW  = (const float*)d_in[7];
  const float* MsW   = (const float*)d_in[8];
  const float* discW = (const float*)d_in[9];
  const float* discb = (const float*)d_in[10];
  float* out = (float*)d_out;
  float* w = (float*)d_ws;

  const size_t SZNN = (size_t)kN * kN;
  const size_t SZNL = (size_t)kN * kLAT;
  float* P   = w;
  float* T   = P + SZNN;
  float* h0  = T + SZNN;
  float* h1  = h0 + SZNL;
  float* xe  = h1 + SZNL;
  float* xea = xe + SZNL;
  float* ha  = xea + SZNL;
  float* ah  = ha + SZNL;
  float* hr  = ah + SZNL;
  float* har = hr + SZNL;
  float* vs  = har + SZNL;
  float* vsa = vs + SZNL;
  float* g   = vsa + SZNL;
  float* ga  = g + SZNL;
  float* hrW = ga + SZNL;
  float* haW = hrW + SZNL;
  float* sns = haW + SZNL;
  float* snt = sns + kN;
  float* rs  = snt + kN;
  float* cs  = rs + kN;
  float* mrs = cs + kN;
  float* acc = mrs + kN;

  hipMemsetAsync(acc, 0, NSLOT * sizeof(float), stream);

  // ---------------- per-slice encode/decode/discriminator losses ----------------
  for (int k = 0; k < 2; k++) {
    const float* x    = feat  + (size_t)k * kN * kIN;
    const float* adj  = adjs  + (size_t)k * SZNN;
    const float* msk  = gmask + (size_t)k * SZNN;
    const float* lab  = labs  + (size_t)k * kN * 2;
    const int*   perm = perms + (size_t)k * kN;
    const float* eW   = encW  + (size_t)k * kIN * kLAT;
    const float* dW   = decW  + (size_t)k * kLAT * kIN;
    float* hk = (k == 0) ? h0 : h1;

    hipMemsetAsync(xe, 0, SZNL * sizeof(float), stream);
    gemm_launch(stream, 0, 0, 1, x, eW, xe, nullptr, nullptr, nullptr, 1.f, nullptr,
                kN, kLAT, kIN, kIN, kLAT, 192);
    gather_k<<<(int)(SZNL / 256), 256, 0, stream>>>(xe, perm, xea);
    hipMemsetAsync(hk, 0, SZNL * sizeof(float), stream);
    gemm_launch(stream, 0, 0, 1, adj, xe, hk, nullptr, nullptr, nullptr, 1.f, nullptr,
                kN, kLAT, kN, kN, kLAT, 256);
    hipMemsetAsync(ha, 0, SZNL * sizeof(float), stream);
    gemm_launch(stream, 0, 0, 1, adj, xea, ha, nullptr, nullptr, nullptr, 1.f, nullptr,
                kN, kLAT, kN, kN, kLAT, 256);
    hipMemsetAsync(ah, 0, SZNL * sizeof(float), stream);
    gemm_launch(stream, 0, 0, 1, adj, hk, ah, nullptr, nullptr, nullptr, 1.f, nullptr,
                kN, kLAT, kN, kN, kLAT, 256);
    gemm_launch(stream, 0, 0, 2, ah, dW, nullptr, x, nullptr, nullptr, 1.f, &acc[FEAT],
                kN, kIN, kLAT, kLAT, kIN, kLAT);
    relu_k<<<(int)(SZNL / 256), 256, 0, stream>>>(hk, hr, (int)SZNL);
    relu_k<<<(int)(SZNL / 256), 256, 0, stream>>>(ha, har, (int)SZNL);
    rowop_k<<<kN, 256, 0, stream>>>((float*)msk, mrs, 2);
    hipMemsetAsync(vs, 0, SZNL * sizeof(float), stream);
    gemm_launch(stream, 0, 0, 1, msk, hr, vs, nullptr, nullptr, nullptr, 1.f, nullptr,
                kN, kLAT, kN, kN, kLAT, 256);
    hipMemsetAsync(vsa, 0, SZNL * sizeof(float), stream);
    gemm_launch(stream, 0, 0, 1, msk, har, vsa, nullptr, nullptr, nullptr, 1.f, nullptr,
                kN, kLAT, kN, kN, kLAT, 256);
    readout_k<<<kN, 64, 0, stream>>>(vs, mrs, g);
    readout_k<<<kN, 64, 0, stream>>>(vsa, mrs, ga);
    gemm_launch(stream, 0, 0, 0, hr, discW, hrW, nullptr, nullptr, nullptr, 1.f, nullptr,
                kN, kLAT, kLAT, kLAT, kLAT, kLAT);
    gemm_launch(stream, 0, 0, 0, har, discW, haW, nullptr, nullptr, nullptr, 1.f, nullptr,
                kN, kLAT, kLAT, kLAT, kLAT, kLAT);
    disc_k<<<kN, 64, 0, stream>>>(g, ga, hrW, haW, lab, discb, acc);
  }

  // ---------------- alignment losses ----------------
  const float* f0 = feat;
  const float* f1 = feat + (size_t)kN * kIN;
  const float* D0 = dists;
  const float* D1 = dists + SZNN;

  gemm_launch(stream, 0, 0, 0, h0, MsW, xe, nullptr, nullptr, nullptr, 1.f, nullptr,
              kN, kLAT, kLAT, kLAT, kLAT, kLAT);
  gemm_launch(stream, 0, 0, 0, h1, MsW, xea, nullptr, nullptr, nullptr, 1.f, nullptr,
              kN, kLAT, kLAT, kLAT, kLAT, kLAT);
  gemm_launch(stream, 0, 1, 0, xe, xea, P, nullptr, nullptr, nullptr, 0.125f, nullptr,
              kN, kN, kLAT, kLAT, kLAT, kLAT);
  rowop_k<<<kN, 256, 0, stream>>>(P, nullptr, 0);
  for (int it = 0; it < 3; it++) {
    rowop_k<<<kN, 256, 0, stream>>>(P, nullptr, 1);
    hipMemsetAsync(cs, 0, kN * sizeof(float), stream);
    colsum_k<<<dim3(kN / 256, 32), 256, 0, stream>>>(P, cs);
    colscale_k<<<2048, 256, 0, stream>>>(P, cs);
  }
  rowop_k<<<kN, 256, 0, stream>>>(P, rs, 2);
  hipMemsetAsync(cs, 0, kN * sizeof(float), stream);
  colsum_k<<<dim3(kN / 256, 32), 256, 0, stream>>>(P, cs);
  sqnorm_k<<<(int)(SZNL / 256), 256, 0, stream>>>(h0, sns);
  sqnorm_k<<<(int)(SZNL / 256), 256, 0, stream>>>(h1, snt);
  gemm_launch(stream, 0, 1, 0, h0, h1, T, nullptr, nullptr, nullptr, 1.f, nullptr,
              kN, kN, kLAT, kLAT, kLAT, kLAT);
  alignsp_k<<<4096, 256, 0, stream>>>(P, T, sns, snt, acc);

  // loss_align_fix (bf16 MFMA)
  mfma_launch(stream, 0, 0, 2, P, f1, nullptr, f0, rs, nullptr, &acc[FXA],
              kIN, kN, kN, kIN, kIN, 0);
  mfma_launch(stream, 1, 0, 2, P, f0, nullptr, f1, cs, nullptr, &acc[FXB],
              kIN, kN, kN, kIN, kIN, 0);
  // loss_maintain part 1: T = (D1 @ P^T)/rs[col]; SM1 = sum((D0 - (P@T)/rs)^2) (symmetric)
  mfma_launch(stream, 0, 1, 0, D1, P, T, nullptr, nullptr, rs, nullptr,
              kN, kN, kN, kN, kN, 0);
  mfma_launch(stream, 0, 0, 2, P, T, nullptr, D0, rs, nullptr, &acc[SM1],
              kN, kN, kN, kN, kN, 1);
  // loss_maintain part 2: T = (D0 @ P)/cs[col]; SM2 = sum((D1 - (P^T@T)/cs)^2) (symmetric)
  mfma_launch(stream, 0, 0, 0, D0, P, T, nullptr, nullptr, cs, nullptr,
              kN, kN, kN, kN, kN, 0);
  mfma_launch(stream, 1, 0, 2, P, T, nullptr, D1, cs, nullptr, &acc[SM2],
              kN, kN, kN, kN, kN, 1);

  finalize_k<<<1, 256, 0, stream>>>(acc, cs, out);
}

// Round 3
// 2964.168 us; speedup vs baseline: 3.7581x; 1.5474x over previous
//
#include <hip/hip_runtime.h>
#include <cmath>

// Problem constants
constexpr int kN   = 4096;
constexpr int kIN  = 3000;
constexpr int kINp = 3072;   // kIN padded to 128-multiple
constexpr int kLAT = 64;

enum { SL = 0, FEAT, ALN, FXA, FXB, SM1, SM2, SPS, NSLOT };

typedef __bf16 bf16x8 __attribute__((ext_vector_type(8)));
typedef float f32x4 __attribute__((ext_vector_type(4)));
typedef unsigned short u16x8 __attribute__((ext_vector_type(8)));
typedef unsigned short u16x4 __attribute__((ext_vector_type(4)));

// ---------------- reduction helpers ----------------
template<bool IS_MAX>
__device__ __forceinline__ float blk_red(float v) {
  __shared__ float buf[4];
  #pragma unroll
  for (int s = 32; s > 0; s >>= 1) {
    float o = __shfl_down(v, s, 64);
    v = IS_MAX ? fmaxf(v, o) : (v + o);
  }
  int lane = threadIdx.x & 63, wv = threadIdx.x >> 6, nw = blockDim.x >> 6;
  __syncthreads();
  if (lane == 0) buf[wv] = v;
  __syncthreads();
  float r = buf[0];
  for (int i = 1; i < nw; i++) r = IS_MAX ? fmaxf(r, buf[i]) : (r + buf[i]);
  return r;
}

__device__ __forceinline__ float wave_red_sum(float v) {
  #pragma unroll
  for (int s = 32; s > 0; s >>= 1) v += __shfl_down(v, s, 64);
  return v;
}

// fp32 -> bf16 RNE
__device__ __forceinline__ unsigned short f2bf(float f) {
  unsigned u = __builtin_bit_cast(unsigned, f);
  u += 0x7fffu + ((u >> 16) & 1u);
  return (unsigned short)(u >> 16);
}

// async global->LDS, 16B per lane, LDS dest = wave-uniform base + lane*16
__device__ __forceinline__ void gload16(const unsigned short* g, unsigned short* l) {
  __builtin_amdgcn_global_load_lds(
      (const __attribute__((address_space(1))) unsigned int*)g,
      (__attribute__((address_space(3))) unsigned int*)l, 16, 0, 0);
}

// ================== uniform bf16 MFMA GEMM: C = A @ Bt^T ==================
// A: [4096][K] bf16 row-major (ldA == K). Bt: [Ncpad][K] bf16 row-major (ldBt == K).
// m97 structure: 128x128 tile, BK=32, linear LDS [128][32], global_load_lds w16,
// XCD-bijective swizzle. grid = gx*32 1D blocks of 256.
// EPI 0: C[r*4096+c] = bf16(acc / rowdiv[r])
// EPI 2: slot += wgt * sum over cc<Nc of (X[r*ldX+c] - acc/rowdiv[r]/coldiv[c])^2
//        sym=1 -> upper-tri blocks only, x2 off-diagonal
template<int EPI>
__global__ __launch_bounds__(256)
void bt_mfma_k(const unsigned short* __restrict__ A, const unsigned short* __restrict__ Bt,
               unsigned short* __restrict__ C, const float* __restrict__ X,
               const float* __restrict__ rowdiv, const float* __restrict__ coldiv,
               float* __restrict__ slot, int gx, int Nc, int K, int ldX, int sym)
{
  __shared__ unsigned short AB[2 * 128 * 32];
  unsigned short* As = AB;
  unsigned short* Bs = AB + 128 * 32;

  int nwg = gridDim.x;                       // multiple of 8 by construction
  int orig = blockIdx.x;
  int wg = (orig & 7) * (nwg >> 3) + (orig >> 3);
  int by = wg / gx, bx = wg - by * gx;
  const int row0 = by * 128, col0 = bx * 128;
  if (EPI == 2 && sym && col0 < row0) return;

  const int t = threadIdx.x, l = t & 63, wv = t >> 6;
  const int wr = wv >> 1, wc = wv & 1;
  const int lr = l & 15, lkh = (l >> 4) << 3;

  f32x4 acc[4][4];
  #pragma unroll
  for (int i = 0; i < 4; i++)
    #pragma unroll
    for (int j = 0; j < 4; j++) acc[i][j] = (f32x4){0.f, 0.f, 0.f, 0.f};

  const int srow = l >> 2;            // row within a 16-row chunk
  const int sk   = (l & 3) << 3;      // 8 ushorts = 16B
  const unsigned short* Ab = A  + (size_t)(row0 + srow) * K + sk;
  const unsigned short* Bb = Bt + (size_t)(col0 + srow) * K + sk;

  for (int k0 = 0; k0 < K; k0 += 32) {
    #pragma unroll
    for (int h2 = 0; h2 < 2; h2++) {
      int c = wv * 2 + h2;            // wave-uniform chunk id 0..7
      gload16(Ab + (size_t)c * 16 * K + k0, As + c * 512);
      gload16(Bb + (size_t)c * 16 * K + k0, Bs + c * 512);
    }
    __syncthreads();
    u16x8 af[4], bfv[4];
    #pragma unroll
    for (int mi = 0; mi < 4; mi++)
      af[mi] = *(const u16x8*)&As[(wr * 64 + mi * 16 + lr) * 32 + lkh];
    #pragma unroll
    for (int ni = 0; ni < 4; ni++)
      bfv[ni] = *(const u16x8*)&Bs[(wc * 64 + ni * 16 + lr) * 32 + lkh];
    #pragma unroll
    for (int mi = 0; mi < 4; mi++)
      #pragma unroll
      for (int ni = 0; ni < 4; ni++)
        acc[mi][ni] = __builtin_amdgcn_mfma_f32_16x16x32_bf16(
            __builtin_bit_cast(bf16x8, af[mi]),
            __builtin_bit_cast(bf16x8, bfv[ni]), acc[mi][ni], 0, 0, 0);
    __syncthreads();
  }

  // C/D mapping: col = lane&15, row = (lane>>4)*4 + reg
  const int lcol = l & 15, lrow = (l >> 4) << 2;
  if (EPI == 0) {
    #pragma unroll
    for (int mi = 0; mi < 4; mi++) {
      int rr = row0 + wr * 64 + mi * 16 + lrow;
      #pragma unroll
      for (int ni = 0; ni < 4; ni++) {
        int cc = col0 + wc * 64 + ni * 16 + lcol;
        #pragma unroll
        for (int r = 0; r < 4; r++) {
          float v = acc[mi][ni][r];
          if (rowdiv) v /= rowdiv[rr + r];
          C[(size_t)(rr + r) * 4096 + cc] = f2bf(v);
        }
      }
    }
  } else {
    float part = 0.f;
    #pragma unroll
    for (int mi = 0; mi < 4; mi++) {
      int rr = row0 + wr * 64 + mi * 16 + lrow;
      #pragma unroll
      for (int ni = 0; ni < 4; ni++) {
        int cc = col0 + wc * 64 + ni * 16 + lcol;
        if (cc < Nc) {
          float cd = coldiv ? coldiv[cc] : 1.f;
          #pragma unroll
          for (int r = 0; r < 4; r++) {
            float v = acc[mi][ni][r];
            if (rowdiv) v /= rowdiv[rr + r];
            v /= cd;
            float d = X[(size_t)(rr + r) * ldX + cc] - v;
            part = fmaf(d, d, part);
          }
        }
      }
    }
    part = blk_red<false>(part);
    if (t == 0) {
      float wgt = (sym && col0 > row0) ? 2.f : 1.f;
      atomicAdd(slot, part * wgt);
    }
  }
}

// ---------------- conversion / transpose pre-passes ----------------
__global__ void cvt_k(const float* __restrict__ s, unsigned short* __restrict__ d, int n8)
{
  int i = blockIdx.x * 256 + threadIdx.x;
  if (i < n8) {
    float4 a = ((const float4*)s)[2 * i], b = ((const float4*)s)[2 * i + 1];
    u16x8 w;
    w[0] = f2bf(a.x); w[1] = f2bf(a.y); w[2] = f2bf(a.z); w[3] = f2bf(a.w);
    w[4] = f2bf(b.x); w[5] = f2bf(b.y); w[6] = f2bf(b.z); w[7] = f2bf(b.w);
    ((u16x8*)d)[i] = w;
  }
}

// transpose+convert: src fp32 [R][C] -> dst bf16 [Cpad][R]; pad rows zeroed.
// grid (Cpad/32, R/32), block 256
__global__ void tr_k(const float* __restrict__ src, unsigned short* __restrict__ dst,
                     int R, int C, int Cpad)
{
  __shared__ float tile[32][33];
  int c0 = blockIdx.x * 32, r0 = blockIdx.y * 32;
  int tr_ = threadIdx.x >> 3, tc4 = (threadIdx.x & 7) << 2;
  #pragma unroll
  for (int j = 0; j < 4; j++) {
    int c = c0 + tc4 + j;
    tile[tr_][tc4 + j] = (c < C) ? src[(size_t)(r0 + tr_) * C + c] : 0.f;
  }
  __syncthreads();
  u16x4 wv;
  #pragma unroll
  for (int j = 0; j < 4; j++) wv[j] = f2bf(tile[tc4 + j][tr_]);
  *(u16x4*)&dst[(size_t)(c0 + tr_) * R + r0 + tc4] = wv;
}

// ---------------- generic tiled fp32 GEMM (skinny work) ----------------
// EPI 0: store C=acc*alpha (ldC). EPI 1: atomicAdd into pre-zeroed C (ldC).
// EPI 3: align+sparsity epilogue: acc = h0.h1^T tile; X=P (ld=ldC);
//        rowdiv=sns, coldiv=snt; slot = acc-array base (ALN, SPS slots).
template<int TA, int TB, int EPI>
__global__ __launch_bounds__(256)
void gemm_k(const float* __restrict__ A, const float* __restrict__ B,
            float* __restrict__ C, const float* __restrict__ X,
            const float* __restrict__ rowdiv, const float* __restrict__ coldiv,
            float alpha, float* __restrict__ slot,
            int M, int Nc, int K, int ldA, int ldB, int ldC, int kchunk)
{
  __shared__ float As[16][68];
  __shared__ float Bs[16][68];
  int tid = threadIdx.x;
  int tx = tid & 15, ty = tid >> 4;
  int row0 = blockIdx.y * 64, col0 = blockIdx.x * 64;
  int kb = blockIdx.z * kchunk;
  int ke = (kb + kchunk < K) ? (kb + kchunk) : K;
  float acc[4][4] = {};

  for (int k0 = kb; k0 < ke; k0 += 16) {
    bool kfull = (k0 + 16 <= ke);
    if (TA == 0) {
      int m = tid >> 2, kk = (tid & 3) << 2;
      const float* ap = A + (size_t)(row0 + m) * ldA + k0 + kk;
      if (kfull) {
        float4 v = *(const float4*)ap;
        As[kk + 0][m] = v.x; As[kk + 1][m] = v.y; As[kk + 2][m] = v.z; As[kk + 3][m] = v.w;
      } else {
        #pragma unroll
        for (int i = 0; i < 4; i++)
          As[kk + i][m] = (k0 + kk + i < ke) ? ap[i] : 0.f;
      }
    }
    if (TB == 0) {
      int kk = tid >> 4, c = (tid & 15) << 2;
      const float* bp = B + (size_t)(k0 + kk) * ldB + col0 + c;
      bool kok = (k0 + kk < ke);
      if (kok && (col0 + 64 <= Nc)) {
        *(float4*)&Bs[kk][c] = *(const float4*)bp;
      } else {
        #pragma unroll
        for (int i = 0; i < 4; i++)
          Bs[kk][c + i] = (kok && (col0 + c + i < Nc)) ? bp[i] : 0.f;
      }
    } else {
      int c = tid >> 2, kk = (tid & 3) << 2;
      const float* bp = B + (size_t)(col0 + c) * ldB + k0 + kk;
      bool cok = (col0 + c < Nc);
      if (cok && kfull) {
        float4 v = *(const float4*)bp;
        Bs[kk + 0][c] = v.x; Bs[kk + 1][c] = v.y; Bs[kk + 2][c] = v.z; Bs[kk + 3][c] = v.w;
      } else {
        #pragma unroll
        for (int i = 0; i < 4; i++)
          Bs[kk + i][c] = (cok && (k0 + kk + i < ke)) ? bp[i] : 0.f;
      }
    }
    __syncthreads();
    #pragma unroll
    for (int kk = 0; kk < 16; kk++) {
      float4 a4 = *(const float4*)&As[kk][ty << 2];
      float4 b4 = *(const float4*)&Bs[kk][tx << 2];
      float av[4] = {a4.x, a4.y, a4.z, a4.w};
      float bv[4] = {b4.x, b4.y, b4.z, b4.w};
      #pragma unroll
      for (int i = 0; i < 4; i++)
        #pragma unroll
        for (int j = 0; j < 4; j++)
          acc[i][j] = fmaf(av[i], bv[j], acc[i][j]);
    }
    __syncthreads();
  }

  if (EPI == 0) {
    #pragma unroll
    for (int i = 0; i < 4; i++) {
      int r = row0 + (ty << 2) + i;
      #pragma unroll
      for (int j = 0; j < 4; j++) {
        int c = col0 + (tx << 2) + j;
        if (c < Nc) C[(size_t)r * ldC + c] = acc[i][j] * alpha;
      }
    }
  } else if (EPI == 1) {
    #pragma unroll
    for (int i = 0; i < 4; i++) {
      int r = row0 + (ty << 2) + i;
      #pragma unroll
      for (int j = 0; j < 4; j++) {
        int c = col0 + (tx << 2) + j;
        if (c < Nc) atomicAdd(&C[(size_t)r * ldC + c], acc[i][j]);
      }
    }
  } else if (EPI == 3) {
    float a = 0.f, sp = 0.f;
    #pragma unroll
    for (int i = 0; i < 4; i++) {
      int r = row0 + (ty << 2) + i;
      #pragma unroll
      for (int j = 0; j < 4; j++) {
        int c = col0 + (tx << 2) + j;
        float g = acc[i][j];
        float p = X[(size_t)r * ldC + c];
        float d2 = rowdiv[r] + coldiv[c] - 2.f * g;
        a = fmaf(p, sqrtf(fmaxf(d2, 1e-12f)), a);
        sp = fmaf(p, logf(p + 1e-10f), sp);
      }
    }
    a = blk_red<false>(a);
    sp = blk_red<false>(sp);
    if (tid == 0) { atomicAdd(&slot[ALN], a); atomicAdd(&slot[SPS], sp); }
  }
}

// ---------------- row ops on P (one block per row) ----------------
__global__ __launch_bounds__(256)
void rowop_k(float* __restrict__ Pm, float* __restrict__ vec, int mode)
{
  int i = blockIdx.x, tid = threadIdx.x;
  float4* prow = (float4*)(Pm + (size_t)i * kN);
  float4 r[4];
  #pragma unroll
  for (int t = 0; t < 4; t++) r[t] = prow[tid + t * 256];

  if (mode == 0) {
    float m = -3.4e38f;
    #pragma unroll
    for (int t = 0; t < 4; t++)
      m = fmaxf(m, fmaxf(fmaxf(r[t].x, r[t].y), fmaxf(r[t].z, r[t].w)));
    m = blk_red<true>(m);
    float s = 0.f;
    #pragma unroll
    for (int t = 0; t < 4; t++) {
      r[t].x = expf(r[t].x - m); r[t].y = expf(r[t].y - m);
      r[t].z = expf(r[t].z - m); r[t].w = expf(r[t].w - m);
      s += r[t].x + r[t].y + r[t].z + r[t].w;
    }
    s = blk_red<false>(s);
    float f = 1.f / (s * (float)kN);
    #pragma unroll
    for (int t = 0; t < 4; t++) {
      r[t].x *= f; r[t].y *= f; r[t].z *= f; r[t].w *= f;
      prow[tid + t * 256] = r[t];
    }
  } else if (mode == 1) {
    float s = 0.f;
    #pragma unroll
    for (int t = 0; t < 4; t++) s += r[t].x + r[t].y + r[t].z + r[t].w;
    s = blk_red<false>(s);
    float f = 1.f / ((float)kN * s);
    #pragma unroll
    for (int t = 0; t < 4; t++) {
      r[t].x *= f; r[t].y *= f; r[t].z *= f; r[t].w *= f;
      prow[tid + t * 256] = r[t];
    }
  } else {
    float s = 0.f;
    #pragma unroll
    for (int t = 0; t < 4; t++) s += r[t].x + r[t].y + r[t].z + r[t].w;
    s = blk_red<false>(s);
    if (tid == 0) vec[i] = s;
  }
}

__global__ void colsum_k(const float* __restrict__ Pm, float* __restrict__ cs)
{
  int j = blockIdx.x * 256 + threadIdx.x;
  int i0 = blockIdx.y * (kN / 32);
  float s = 0.f;
  for (int i = i0; i < i0 + kN / 32; i++) s += Pm[(size_t)i * kN + j];
  atomicAdd(&cs[j], s);
}

__global__ void colscale_k(float* __restrict__ Pm, const float* __restrict__ cs)
{
  size_t t = (size_t)blockIdx.x * blockDim.x + threadIdx.x;
  size_t total = (size_t)kN * kN / 4;
  size_t stride = (size_t)gridDim.x * blockDim.x;
  for (; t < total; t += stride) {
    float4 v = ((float4*)Pm)[t];
    int j = (int)((t * 4) & (kN - 1));
    v.x /= ((float)kN * cs[j + 0]);
    v.y /= ((float)kN * cs[j + 1]);
    v.z /= ((float)kN * cs[j + 2]);
    v.w /= ((float)kN * cs[j + 3]);
    ((float4*)Pm)[t] = v;
  }
}

__global__ void relu_k(const float* __restrict__ in, float* __restrict__ out, int n)
{
  int i = blockIdx.x * blockDim.x + threadIdx.x;
  if (i < n) out[i] = fmaxf(in[i], 0.f);
}

// XP[i][64+j] = XP[perm[i]][j]   (in-place, disjoint column halves)
__global__ void gather_k(float* __restrict__ XP, const int* __restrict__ perm)
{
  int gid = blockIdx.x * 256 + threadIdx.x;
  int i = gid >> 6, j = gid & 63;
  XP[(size_t)i * 128 + 64 + j] = XP[(size_t)perm[i] * 128 + j];
}

// per-row squared L2 of [4096][ld] matrix, first 64 cols (one wave per row)
__global__ void sqnorm_k(const float* __restrict__ H, int ld, float* __restrict__ outv)
{
  int gid = blockIdx.x * 256 + threadIdx.x;
  int row = gid >> 6, j = gid & 63;
  float v = H[(size_t)row * ld + j];
  float p = wave_red_sum(v * v);
  if (j == 0) outv[row] = p;
}

// VS viewed as [8192][64]; row 2r = vs[r], 2r+1 = vsa[r]; mrs indexed by r
__global__ void readout_k(const float* __restrict__ vs2, const float* __restrict__ mrs,
                          float* __restrict__ g2)
{
  int q = blockIdx.x, j = threadIdx.x;
  float v = vs2[(size_t)q * 64 + j] / mrs[q >> 1];
  float p = v * v;
  #pragma unroll
  for (int s = 1; s < 64; s <<= 1) p += __shfl_xor(p, s, 64);
  float nrm = sqrtf(p);
  v = v / fmaxf(nrm, 1e-12f);
  g2[(size_t)q * 64 + j] = 1.f / (1.f + expf(-v));
}

__device__ __forceinline__ float bce_term(float x, float y) {
  return fmaxf(x, 0.f) - x * y + log1pf(expf(-fabsf(x)));
}

// G2/W2 are [8192][64]: rows 2i = (g, hrW), 2i+1 = (ga, haW)
__global__ void disc_k(const float* __restrict__ G2, const float* __restrict__ W2,
                       const float* __restrict__ lab, const float* __restrict__ bptr,
                       float* __restrict__ acc)
{
  int i = blockIdx.x, j = threadIdx.x;
  float gj  = G2[(size_t)(2 * i) * 64 + j];
  float gaj = G2[(size_t)(2 * i + 1) * 64 + j];
  float hw  = W2[(size_t)(2 * i) * 64 + j];
  float haw = W2[(size_t)(2 * i + 1) * 64 + j];
  float s1 = hw * gj, s2 = haw * gj, s1a = haw * gaj, s2a = hw * gaj;
  #pragma unroll
  for (int s = 1; s < 64; s <<= 1) {
    s1  += __shfl_xor(s1, s, 64);
    s2  += __shfl_xor(s2, s, 64);
    s1a += __shfl_xor(s1a, s, 64);
    s2a += __shfl_xor(s2a, s, 64);
  }
  if (j == 0) {
    float b = bptr[0];
    float y0 = lab[i * 2 + 0], y1 = lab[i * 2 + 1];
    float t = bce_term(s1 + b, y0) + bce_term(s2 + b, y1)
            + bce_term(s1a + b, y0) + bce_term(s2a + b, y1);
    atomicAdd(&acc[SL], t);
  }
}

__global__ __launch_bounds__(256)
void finalize_k(const float* __restrict__ acc, const float* __restrict__ cs,
                float* __restrict__ out)
{
  int tid = threadIdx.x;
  float invm2 = 1.f / (float)kN;
  float t = 0.f;
  for (int j = tid; j < kN; j += 256) {
    float q = cs[j];
    t += q * (logf(q) - invm2);
  }
  t = blk_red<false>(t);
  if (tid == 0) {
    float kld_pq = t * invm2;
    float kld_pp = invm2 * (logf(invm2) - invm2);
    out[0] = acc[SL] / (2.f * (float)kN);
    out[1] = acc[FEAT] / ((float)kN * (float)kIN);
    out[2] = acc[ALN];
    out[3] = (acc[FXA] + acc[FXB]) / ((float)kN * (float)kIN);
    out[4] = sqrtf(acc[SM1]) / (float)kN + sqrtf(acc[SM2]) / (float)kN;
    out[5] = (kld_pq - kld_pp) * (float)kN;
    out[6] = -acc[SPS];
  }
}

// ---------------- host-side dispatch ----------------
static void gemm_launch(hipStream_t st, int TA, int TB, int EPI,
                        const float* A, const float* B, float* C, const float* X,
                        const float* rowdiv, const float* coldiv, float alpha, float* slot,
                        int M, int Ncc, int K, int ldA, int ldB, int ldC, int kchunk)
{
  dim3 grid((Ncc + 63) / 64, M / 64, (K + kchunk - 1) / kchunk);
  dim3 blk(256, 1, 1);
  #define GL(ta, tb, epi) gemm_k<ta, tb, epi><<<grid, blk, 0, st>>>( \
      A, B, C, X, rowdiv, coldiv, alpha, slot, M, Ncc, K, ldA, ldB, ldC, kchunk)
  if      (TA == 0 && TB == 0 && EPI == 0) GL(0, 0, 0);
  else if (TA == 0 && TB == 0 && EPI == 1) GL(0, 0, 1);
  else if (TA == 0 && TB == 1 && EPI == 0) GL(0, 1, 0);
  else if (TA == 0 && TB == 1 && EPI == 3) GL(0, 1, 3);
  #undef GL
}

static void bt_launch(hipStream_t st, int EPI,
                      const unsigned short* A, const unsigned short* Bt,
                      unsigned short* C, const float* X,
                      const float* rowdiv, const float* coldiv, float* slot,
                      int gx, int Nc, int K, int ldX, int sym)
{
  int nwg = gx * 32;
  if (EPI == 0)
    bt_mfma_k<0><<<nwg, 256, 0, st>>>(A, Bt, C, X, rowdiv, coldiv, slot, gx, Nc, K, ldX, sym);
  else
    bt_mfma_k<2><<<nwg, 256, 0, st>>>(A, Bt, C, X, rowdiv, coldiv, slot, gx, Nc, K, ldX, sym);
}

extern "C" void kernel_launch(void* const* d_in, const int* in_sizes, int n_in,
                              void* d_out, int out_size, void* d_ws, size_t ws_size,
                              hipStream_t stream)
{
  (void)in_sizes; (void)n_in; (void)out_size; (void)ws_size;
  const float* feat  = (const float*)d_in[0];
  const float* adjs  = (const float*)d_in[1];
  const float* gmask = (const float*)d_in[2];
  const float* labs  = (const float*)d_in[3];
  const float* dists = (const float*)d_in[4];
  const int*   perms = (const int*)d_in[5];
  const float* encW  = (const float*)d_in[6];
  const float* decW  = (const float*)d_in[7];
  const float* MsW   = (const float*)d_in[8];
  const float* discW = (const float*)d_in[9];
  const float* discb = (const float*)d_in[10];
  float* out = (float*)d_out;

  const size_t SZNN = (size_t)kN * kN;

  // ---- workspace bump allocator (16B aligned) ----
  char* cur = (char*)d_ws;
  auto alloc = [&](size_t bytes) {
    char* p = cur;
    cur += (bytes + 15) & ~(size_t)15;
    return p;
  };
  float* P            = (float*)alloc(SZNN * 4);
  unsigned short* Pb  = (unsigned short*)alloc(SZNN * 2);
  unsigned short* PbT = (unsigned short*)alloc(SZNN * 2);
  unsigned short* Db  = (unsigned short*)alloc(SZNN * 2);
  unsigned short* Tb  = (unsigned short*)alloc(SZNN * 2);
  unsigned short* ftb = (unsigned short*)alloc((size_t)kINp * kN * 2);
  unsigned short* dWtb= (unsigned short*)alloc((size_t)kINp * kLAT * 2);
  unsigned short* ahb = (unsigned short*)alloc((size_t)kN * kLAT * 2);
  float* XP  = (float*)alloc((size_t)kN * 128 * 4);
  float* HH0 = (float*)alloc((size_t)kN * 128 * 4);
  float* HH1 = (float*)alloc((size_t)kN * 128 * 4);
  float* HR  = (float*)alloc((size_t)kN * 128 * 4);
  float* VS  = (float*)alloc((size_t)kN * 128 * 4);
  float* G2  = (float*)alloc((size_t)kN * 128 * 4);
  float* W2  = (float*)alloc((size_t)kN * 128 * 4);
  float* SM_ = (float*)alloc((size_t)kN * kLAT * 4);
  float* TM_ = (float*)alloc((size_t)kN * kLAT * 4);
  float* ah  = (float*)alloc((size_t)kN * kLAT * 4);
  float* sns = (float*)alloc(kN * 4);
  float* snt = (float*)alloc(kN * 4);
  float* rs  = (float*)alloc(kN * 4);
  float* cs  = (float*)alloc(kN * 4);
  float* mrs = (float*)alloc(kN * 4);
  float* acc = (float*)alloc(NSLOT * 4);

  hipMemsetAsync(acc, 0, NSLOT * sizeof(float), stream);

  // ---------------- per-slice losses ----------------
  for (int k = 0; k < 2; k++) {
    const float* x    = feat  + (size_t)k * kN * kIN;
    const float* adj  = adjs  + (size_t)k * SZNN;
    const float* msk  = gmask + (size_t)k * SZNN;
    const float* lab  = labs  + (size_t)k * kN * 2;
    const int*   perm = perms + (size_t)k * kN;
    const float* eW   = encW  + (size_t)k * kIN * kLAT;
    const float* dW   = decW  + (size_t)k * kLAT * kIN;
    float* HHk = (k == 0) ? HH0 : HH1;

    // XP cols 0..63 = x @ encW (split-K atomic)
    hipMemsetAsync(XP, 0, (size_t)kN * 128 * 4, stream);
    gemm_launch(stream, 0, 0, 1, x, eW, XP, nullptr, nullptr, nullptr, 1.f, nullptr,
                kN, kLAT, kIN, kIN, kLAT, 128, 192);
    // XP cols 64..127 = xe[perm]
    gather_k<<<kN * 64 / 256, 256, 0, stream>>>(XP, perm);
    // HH = adj @ XP  -> [h | h_a]
    hipMemsetAsync(HHk, 0, (size_t)kN * 128 * 4, stream);
    gemm_launch(stream, 0, 0, 1, adj, XP, HHk, nullptr, nullptr, nullptr, 1.f, nullptr,
                kN, 128, kN, kN, 128, 128, 256);
    // ah = adj @ h
    hipMemsetAsync(ah, 0, (size_t)kN * kLAT * 4, stream);
    gemm_launch(stream, 0, 0, 1, adj, HHk, ah, nullptr, nullptr, nullptr, 1.f, nullptr,
                kN, kLAT, kN, kN, 128, kLAT, 128);
    // FEAT via MFMA: sum((x - ah@decW)^2)
    cvt_k<<<(kN * kLAT / 8 + 255) / 256, 256, 0, stream>>>(ah, ahb, kN * kLAT / 8);
    tr_k<<<dim3(kINp / 32, 2), 256, 0, stream>>>(dW, dWtb, kLAT, kIN, kINp);
    bt_launch(stream, 2, ahb, dWtb, nullptr, x, nullptr, nullptr, &acc[FEAT],
              kINp / 128, kIN, kLAT, kIN, 0);
    // relu both halves
    relu_k<<<kN * 128 / 256, 256, 0, stream>>>(HHk, HR, kN * 128);
    // mask rowsums
    rowop_k<<<kN, 256, 0, stream>>>((float*)msk, mrs, 2);
    // VS = msk @ HR  -> [vsum | vsum_a]
    hipMemsetAsync(VS, 0, (size_t)kN * 128 * 4, stream);
    gemm_launch(stream, 0, 0, 1, msk, HR, VS, nullptr, nullptr, nullptr, 1.f, nullptr,
                kN, 128, kN, kN, 128, 128, 256);
    // g2 = sigmoid(normalize(vs/mrs)) on [8192][64] view
    readout_k<<<2 * kN, 64, 0, stream>>>(VS, mrs, G2);
    // W2 = [hr;har]_interleaved @ discW   (HR viewed as [8192][64])
    gemm_launch(stream, 0, 0, 0, HR, discW, W2, nullptr, nullptr, nullptr, 1.f, nullptr,
                2 * kN, kLAT, kLAT, kLAT, kLAT, kLAT, kLAT);
    disc_k<<<kN, 64, 0, stream>>>(G2, W2, lab, discb, acc);
  }

  // ---------------- alignment losses ----------------
  const float* f0 = feat;
  const float* f1 = feat + (size_t)kN * kIN;
  const float* D0 = dists;
  const float* D1 = dists + SZNN;

  // srcM/tgtM = h @ M
  gemm_launch(stream, 0, 0, 0, HH0, MsW, SM_, nullptr, nullptr, nullptr, 1.f, nullptr,
              kN, kLAT, kLAT, 128, kLAT, kLAT, kLAT);
  gemm_launch(stream, 0, 0, 0, HH1, MsW, TM_, nullptr, nullptr, nullptr, 1.f, nullptr,
              kN, kLAT, kLAT, 128, kLAT, kLAT, kLAT);
  // P = srcM @ tgtM^T / 8
  gemm_launch(stream, 0, 1, 0, SM_, TM_, P, nullptr, nullptr, nullptr, 0.125f, nullptr,
              kN, kN, kLAT, kLAT, kLAT, kN, kLAT);
  rowop_k<<<kN, 256, 0, stream>>>(P, nullptr, 0);
  for (int it = 0; it < 3; it++) {
    rowop_k<<<kN, 256, 0, stream>>>(P, nullptr, 1);
    hipMemsetAsync(cs, 0, kN * sizeof(float), stream);
    colsum_k<<<dim3(kN / 256, 32), 256, 0, stream>>>(P, cs);
    colscale_k<<<2048, 256, 0, stream>>>(P, cs);
  }
  rowop_k<<<kN, 256, 0, stream>>>(P, rs, 2);
  hipMemsetAsync(cs, 0, kN * sizeof(float), stream);
  colsum_k<<<dim3(kN / 256, 32), 256, 0, stream>>>(P, cs);

  // bf16 copies of final P
  cvt_k<<<(int)(SZNN / 8 / 256), 256, 0, stream>>>(P, Pb, (int)(SZNN / 8));
  tr_k<<<dim3(kN / 32, kN / 32), 256, 0, stream>>>(P, PbT, kN, kN, kN);

  // loss_align + loss_sparsity fused into h0.h1^T GEMM epilogue
  sqnorm_k<<<kN * 64 / 256, 256, 0, stream>>>(HH0, 128, sns);
  sqnorm_k<<<kN * 64 / 256, 256, 0, stream>>>(HH1, 128, snt);
  gemm_launch(stream, 0, 1, 3, HH0, HH1, nullptr, P, sns, snt, 1.f, acc,
              kN, kN, kLAT, 128, 128, kN, kLAT);

  // loss_align_fix
  tr_k<<<dim3(kINp / 32, kN / 32), 256, 0, stream>>>(f1, ftb, kN, kIN, kINp);
  bt_launch(stream, 2, Pb, ftb, nullptr, f0, rs, nullptr, &acc[FXA],
            kINp / 128, kIN, kN, kIN, 0);
  tr_k<<<dim3(kINp / 32, kN / 32), 256, 0, stream>>>(f0, ftb, kN, kIN, kINp);
  bt_launch(stream, 2, PbT, ftb, nullptr, f1, cs, nullptr, &acc[FXB],
            kINp / 128, kIN, kN, kIN, 0);

  // loss_maintain 1: Tb = (P@D1)/rs[row]; SM1 = sum((D0 - (Tb@P^T)/rs[col])^2), symmetric
  cvt_k<<<(int)(SZNN / 8 / 256), 256, 0, stream>>>(D1, Db, (int)(SZNN / 8));
  bt_launch(stream, 0, Pb, Db, Tb, nullptr, rs, nullptr, nullptr,
            kN / 128, kN, kN, 0, 0);
  bt_launch(stream, 2, Tb, Pb, nullptr, D0, nullptr, rs, &acc[SM1],
            kN / 128, kN, kN, kN, 1);
  // loss_maintain 2: Tb = (P^T@D0)/cs[row]; SM2 = sum((D1 - (Tb@P)/cs[col])^2), symmetric
  cvt_k<<<(int)(SZNN / 8 / 256), 256, 0, stream>>>(D0, Db, (int)(SZNN / 8));
  bt_launch(stream, 0, PbT, Db, Tb, nullptr, cs, nullptr, nullptr,
            kN / 128, kN, kN, 0, 0);
  bt_launch(stream, 2, Tb, PbT, nullptr, D1, nullptr, cs, &acc[SM2],
            kN / 128, kN, kN, kN, 1);

  finalize_k<<<1, 256, 0, stream>>>(acc, cs, out);
}

// Round 4
// 2556.496 us; speedup vs baseline: 4.3574x; 1.1595x over previous
//
#include <hip/hip_runtime.h>
#include <cmath>

// Problem constants
constexpr int kN   = 4096;
constexpr int kIN  = 3000;
constexpr int kINp = 3072;   // kIN padded to 128-multiple
constexpr int kLAT = 64;

enum { SL = 0, FEAT, ALN, FXA, FXB, SM1, SM2, SPS, NSLOT };

typedef __bf16 bf16x8 __attribute__((ext_vector_type(8)));
typedef float f32x4 __attribute__((ext_vector_type(4)));
typedef unsigned short u16x8 __attribute__((ext_vector_type(8)));
typedef unsigned short u16x4 __attribute__((ext_vector_type(4)));

// ---------------- reduction helpers ----------------
template<bool IS_MAX>
__device__ __forceinline__ float blk_red(float v) {
  __shared__ float buf[4];
  #pragma unroll
  for (int s = 32; s > 0; s >>= 1) {
    float o = __shfl_down(v, s, 64);
    v = IS_MAX ? fmaxf(v, o) : (v + o);
  }
  int lane = threadIdx.x & 63, wv = threadIdx.x >> 6, nw = blockDim.x >> 6;
  __syncthreads();
  if (lane == 0) buf[wv] = v;
  __syncthreads();
  float r = buf[0];
  for (int i = 1; i < nw; i++) r = IS_MAX ? fmaxf(r, buf[i]) : (r + buf[i]);
  return r;
}

__device__ __forceinline__ float wave_red_sum(float v) {
  #pragma unroll
  for (int s = 32; s > 0; s >>= 1) v += __shfl_down(v, s, 64);
  return v;
}

// fp32 -> bf16 RNE
__device__ __forceinline__ unsigned short f2bf(float f) {
  unsigned u = __builtin_bit_cast(unsigned, f);
  u += 0x7fffu + ((u >> 16) & 1u);
  return (unsigned short)(u >> 16);
}

// async global->LDS, 16B per lane
__device__ __forceinline__ void gload16(const unsigned short* g, unsigned short* l) {
  __builtin_amdgcn_global_load_lds(
      (const __attribute__((address_space(1))) unsigned int*)g,
      (__attribute__((address_space(3))) unsigned int*)l, 16, 0, 0);
}

// ================== uniform bf16 MFMA GEMM: C = A @ Bt^T ==================
// A: [4096][K] bf16 (ldA=K). Bt: [Ncpad][K] bf16 (ldBt=K). M fixed 4096.
// 128x128 tile, BK=32, double-buffered linear LDS, global_load_lds w16,
// counted vmcnt(4) pipeline (T3/T4 minimal), raw s_barrier.
// Tile mapping: dense -> per-XCD 4-row strip, column-major within strip.
//               sym   -> 528 upper-tri tiles, bijective per-XCD chunks.
// EPI 0: C[r*4096+c] = bf16(acc / rowdiv[r])
// EPI 2: slot += wgt * sum_{cc<Nc} (X[r*ldX+c] - acc/rowdiv[r]/coldiv[c])^2
template<int EPI>
__global__ __launch_bounds__(256)
void bt_mfma_k(const unsigned short* __restrict__ A, const unsigned short* __restrict__ Bt,
               unsigned short* __restrict__ C, const float* __restrict__ X,
               const float* __restrict__ rowdiv, const float* __restrict__ coldiv,
               float* __restrict__ slot, int gx, int Nc, int K, int ldX, int sym)
{
  __shared__ unsigned short AB[2 * 2 * 128 * 32];   // 2 bufs x (A 4096 + B 4096) ushorts

  int orig = blockIdx.x;
  int bx, by;
  if (EPI == 2 && sym) {
    // 528 upper-tri tiles of a 32x32 grid; XCD-chunked bijective (528 = 8*66)
    int x = orig & 7, i = orig >> 3;
    int u = x * 66 + i;
    float disc = 4225.f - 8.f * (float)u;
    by = (int)((65.f - sqrtf(fmaxf(disc, 0.f))) * 0.5f);
    while (by > 0 && 32 * by - by * (by - 1) / 2 > u) by--;
    while (32 * (by + 1) - (by + 1) * by / 2 <= u) by++;
    bx = by + (u - (32 * by - by * (by - 1) / 2));
  } else {
    // strip: XCD x owns rows 4x..4x+3, column-major traversal
    int x = orig & 7, tt = orig >> 3;
    bx = tt >> 2;
    by = x * 4 + (tt & 3);
  }
  const int row0 = by * 128, col0 = bx * 128;

  const int t = threadIdx.x, l = t & 63, wv = t >> 6;
  const int wr = wv >> 1, wc = wv & 1;
  const int lr = l & 15, lkh = (l >> 4) << 3;

  f32x4 acc[4][4];
  #pragma unroll
  for (int i = 0; i < 4; i++)
    #pragma unroll
    for (int j = 0; j < 4; j++) acc[i][j] = (f32x4){0.f, 0.f, 0.f, 0.f};

  const int srow = l >> 2;            // row within a 16-row chunk
  const int sk   = (l & 3) << 3;      // 8 ushorts = 16B
  const unsigned short* Ab = A  + (size_t)(row0 + srow) * K + sk;
  const unsigned short* Bb = Bt + (size_t)(col0 + srow) * K + sk;

  const int NT = K >> 5;              // K/32 tiles

  auto STAGE = [&](int kt, int buf) {
    unsigned short* As = AB + buf * 8192;
    unsigned short* Bs = As + 4096;
    int k0 = kt << 5;
    #pragma unroll
    for (int h2 = 0; h2 < 2; h2++) {
      int c = wv * 2 + h2;            // wave-uniform chunk id 0..7
      gload16(Ab + (size_t)c * 16 * K + k0, As + c * 512);
      gload16(Bb + (size_t)c * 16 * K + k0, Bs + c * 512);
    }
  };

  STAGE(0, 0);
  if (NT > 1) STAGE(1, 1);
  int cur = 0;

  for (int kt = 0; kt < NT; ++kt) {
    if (kt + 1 < NT) { asm volatile("s_waitcnt vmcnt(4)" ::: "memory"); }
    else             { asm volatile("s_waitcnt vmcnt(0)" ::: "memory"); }
    __builtin_amdgcn_sched_barrier(0);
    __builtin_amdgcn_s_barrier();

    const unsigned short* As = AB + cur * 8192;
    const unsigned short* Bs = As + 4096;
    u16x8 af[4], bfv[4];
    #pragma unroll
    for (int mi = 0; mi < 4; mi++)
      af[mi] = *(const u16x8*)&As[(wr * 64 + mi * 16 + lr) * 32 + lkh];
    #pragma unroll
    for (int ni = 0; ni < 4; ni++)
      bfv[ni] = *(const u16x8*)&Bs[(wc * 64 + ni * 16 + lr) * 32 + lkh];
    #pragma unroll
    for (int mi = 0; mi < 4; mi++)
      #pragma unroll
      for (int ni = 0; ni < 4; ni++)
        acc[mi][ni] = __builtin_amdgcn_mfma_f32_16x16x32_bf16(
            __builtin_bit_cast(bf16x8, af[mi]),
            __builtin_bit_cast(bf16x8, bfv[ni]), acc[mi][ni], 0, 0, 0);

    __builtin_amdgcn_s_barrier();     // buf[cur] reads done -> safe to overwrite
    if (kt + 2 < NT) STAGE(kt + 2, cur);
    cur ^= 1;
  }

  // C/D mapping: col = lane&15, row = (lane>>4)*4 + reg
  const int lcol = l & 15, lrow = (l >> 4) << 2;
  if (EPI == 0) {
    #pragma unroll
    for (int mi = 0; mi < 4; mi++) {
      int rr = row0 + wr * 64 + mi * 16 + lrow;
      #pragma unroll
      for (int ni = 0; ni < 4; ni++) {
        int cc = col0 + wc * 64 + ni * 16 + lcol;
        #pragma unroll
        for (int r = 0; r < 4; r++) {
          float v = acc[mi][ni][r];
          if (rowdiv) v /= rowdiv[rr + r];
          C[(size_t)(rr + r) * 4096 + cc] = f2bf(v);
        }
      }
    }
  } else {
    float part = 0.f;
    #pragma unroll
    for (int mi = 0; mi < 4; mi++) {
      int rr = row0 + wr * 64 + mi * 16 + lrow;
      #pragma unroll
      for (int ni = 0; ni < 4; ni++) {
        int cc = col0 + wc * 64 + ni * 16 + lcol;
        if (cc < Nc) {
          float cd = coldiv ? coldiv[cc] : 1.f;
          #pragma unroll
          for (int r = 0; r < 4; r++) {
            float v = acc[mi][ni][r];
            if (rowdiv) v /= rowdiv[rr + r];
            v /= cd;
            float d = X[(size_t)(rr + r) * ldX + cc] - v;
            part = fmaf(d, d, part);
          }
        }
      }
    }
    part = blk_red<false>(part);
    if (t == 0) {
      float wgt = (sym && col0 > row0) ? 2.f : 1.f;
      atomicAdd(slot, part * wgt);
    }
  }
}

// ---------------- conversion / transpose pre-passes ----------------
__global__ void cvt_k(const float* __restrict__ s, unsigned short* __restrict__ d, int n8)
{
  int i = blockIdx.x * 256 + threadIdx.x;
  if (i < n8) {
    float4 a = ((const float4*)s)[2 * i], b = ((const float4*)s)[2 * i + 1];
    u16x8 w;
    w[0] = f2bf(a.x); w[1] = f2bf(a.y); w[2] = f2bf(a.z); w[3] = f2bf(a.w);
    w[4] = f2bf(b.x); w[5] = f2bf(b.y); w[6] = f2bf(b.z); w[7] = f2bf(b.w);
    ((u16x8*)d)[i] = w;
  }
}

// transpose+convert: src fp32 [R][C] -> dst bf16 [Cpad][R]; pad rows zeroed.
__global__ void tr_k(const float* __restrict__ src, unsigned short* __restrict__ dst,
                     int R, int C, int Cpad)
{
  __shared__ float tile[32][33];
  int c0 = blockIdx.x * 32, r0 = blockIdx.y * 32;
  int tr_ = threadIdx.x >> 3, tc4 = (threadIdx.x & 7) << 2;
  #pragma unroll
  for (int j = 0; j < 4; j++) {
    int c = c0 + tc4 + j;
    tile[tr_][tc4 + j] = (c < C) ? src[(size_t)(r0 + tr_) * C + c] : 0.f;
  }
  __syncthreads();
  u16x4 wv;
  #pragma unroll
  for (int j = 0; j < 4; j++) wv[j] = f2bf(tile[tc4 + j][tr_]);
  *(u16x4*)&dst[(size_t)(c0 + tr_) * R + r0 + tc4] = wv;
}

// ---------------- generic tiled fp32 GEMM (skinny work) ----------------
template<int TA, int TB, int EPI>
__global__ __launch_bounds__(256)
void gemm_k(const float* __restrict__ A, const float* __restrict__ B,
            float* __restrict__ C, const float* __restrict__ X,
            const float* __restrict__ rowdiv, const float* __restrict__ coldiv,
            float alpha, float* __restrict__ slot,
            int M, int Nc, int K, int ldA, int ldB, int ldC, int kchunk)
{
  __shared__ float As[16][68];
  __shared__ float Bs[16][68];
  int tid = threadIdx.x;
  int tx = tid & 15, ty = tid >> 4;
  int row0 = blockIdx.y * 64, col0 = blockIdx.x * 64;
  int kb = blockIdx.z * kchunk;
  int ke = (kb + kchunk < K) ? (kb + kchunk) : K;
  float acc[4][4] = {};

  for (int k0 = kb; k0 < ke; k0 += 16) {
    bool kfull = (k0 + 16 <= ke);
    if (TA == 0) {
      int m = tid >> 2, kk = (tid & 3) << 2;
      const float* ap = A + (size_t)(row0 + m) * ldA + k0 + kk;
      if (kfull) {
        float4 v = *(const float4*)ap;
        As[kk + 0][m] = v.x; As[kk + 1][m] = v.y; As[kk + 2][m] = v.z; As[kk + 3][m] = v.w;
      } else {
        #pragma unroll
        for (int i = 0; i < 4; i++)
          As[kk + i][m] = (k0 + kk + i < ke) ? ap[i] : 0.f;
      }
    }
    if (TB == 0) {
      int kk = tid >> 4, c = (tid & 15) << 2;
      const float* bp = B + (size_t)(k0 + kk) * ldB + col0 + c;
      bool kok = (k0 + kk < ke);
      if (kok && (col0 + 64 <= Nc)) {
        *(float4*)&Bs[kk][c] = *(const float4*)bp;
      } else {
        #pragma unroll
        for (int i = 0; i < 4; i++)
          Bs[kk][c + i] = (kok && (col0 + c + i < Nc)) ? bp[i] : 0.f;
      }
    } else {
      int c = tid >> 2, kk = (tid & 3) << 2;
      const float* bp = B + (size_t)(col0 + c) * ldB + k0 + kk;
      bool cok = (col0 + c < Nc);
      if (cok && kfull) {
        float4 v = *(const float4*)bp;
        Bs[kk + 0][c] = v.x; Bs[kk + 1][c] = v.y; Bs[kk + 2][c] = v.z; Bs[kk + 3][c] = v.w;
      } else {
        #pragma unroll
        for (int i = 0; i < 4; i++)
          Bs[kk + i][c] = (cok && (k0 + kk + i < ke)) ? bp[i] : 0.f;
      }
    }
    __syncthreads();
    #pragma unroll
    for (int kk = 0; kk < 16; kk++) {
      float4 a4 = *(const float4*)&As[kk][ty << 2];
      float4 b4 = *(const float4*)&Bs[kk][tx << 2];
      float av[4] = {a4.x, a4.y, a4.z, a4.w};
      float bv[4] = {b4.x, b4.y, b4.z, b4.w};
      #pragma unroll
      for (int i = 0; i < 4; i++)
        #pragma unroll
        for (int j = 0; j < 4; j++)
          acc[i][j] = fmaf(av[i], bv[j], acc[i][j]);
    }
    __syncthreads();
  }

  if (EPI == 0) {
    #pragma unroll
    for (int i = 0; i < 4; i++) {
      int r = row0 + (ty << 2) + i;
      #pragma unroll
      for (int j = 0; j < 4; j++) {
        int c = col0 + (tx << 2) + j;
        if (c < Nc) C[(size_t)r * ldC + c] = acc[i][j] * alpha;
      }
    }
  } else if (EPI == 1) {
    #pragma unroll
    for (int i = 0; i < 4; i++) {
      int r = row0 + (ty << 2) + i;
      #pragma unroll
      for (int j = 0; j < 4; j++) {
        int c = col0 + (tx << 2) + j;
        if (c < Nc) atomicAdd(&C[(size_t)r * ldC + c], acc[i][j]);
      }
    }
  } else if (EPI == 3) {
    float a = 0.f, sp = 0.f;
    #pragma unroll
    for (int i = 0; i < 4; i++) {
      int r = row0 + (ty << 2) + i;
      #pragma unroll
      for (int j = 0; j < 4; j++) {
        int c = col0 + (tx << 2) + j;
        float g = acc[i][j];
        float p = X[(size_t)r * ldC + c];
        float d2 = rowdiv[r] + coldiv[c] - 2.f * g;
        a = fmaf(p, sqrtf(fmaxf(d2, 1e-12f)), a);
        sp = fmaf(p, logf(p + 1e-10f), sp);
      }
    }
    a = blk_red<false>(a);
    sp = blk_red<false>(sp);
    if (tid == 0) { atomicAdd(&slot[ALN], a); atomicAdd(&slot[SPS], sp); }
  }
}

// ---------------- fused Sinkhorn passes ----------------
// grid 512 blocks x 256 threads; block handles 8 rows. One pass over P each.
// mode 0: P = softmax(row)/m1; accumulate colsums -> cs_out
// mode 1: v /= (m2*cs_in[j]); s = rowsum; v /= (m1*s); write; colsums -> cs_out
// mode 2: v /= (m2*cs_in[j]); s = rowsum -> rs[row]; write P + Pb(bf16); colsums -> cs_out
__global__ __launch_bounds__(256)
void sink_k(float* __restrict__ P, unsigned short* __restrict__ Pb,
            const float* __restrict__ cs_in, float* __restrict__ cs_out,
            float* __restrict__ rs, int mode)
{
  int tid = threadIdx.x;
  int r0 = blockIdx.x * 8;
  float csl[16] = {};
  float cdiv[16];
  if (mode != 0) {
    #pragma unroll
    for (int t = 0; t < 4; t++) {
      float4 c4 = ((const float4*)cs_in)[tid + t * 256];
      cdiv[4 * t + 0] = 1.f / (4096.f * c4.x);
      cdiv[4 * t + 1] = 1.f / (4096.f * c4.y);
      cdiv[4 * t + 2] = 1.f / (4096.f * c4.z);
      cdiv[4 * t + 3] = 1.f / (4096.f * c4.w);
    }
  }
  for (int rr = 0; rr < 8; rr++) {
    int row = r0 + rr;
    float4* prow = (float4*)(P + (size_t)row * 4096);
    float4 r[4];
    #pragma unroll
    for (int t = 0; t < 4; t++) r[t] = prow[tid + t * 256];

    if (mode == 0) {
      float m = -3.4e38f;
      #pragma unroll
      for (int t = 0; t < 4; t++)
        m = fmaxf(m, fmaxf(fmaxf(r[t].x, r[t].y), fmaxf(r[t].z, r[t].w)));
      m = blk_red<true>(m);
      float s = 0.f;
      #pragma unroll
      for (int t = 0; t < 4; t++) {
        r[t].x = expf(r[t].x - m); r[t].y = expf(r[t].y - m);
        r[t].z = expf(r[t].z - m); r[t].w = expf(r[t].w - m);
        s += r[t].x + r[t].y + r[t].z + r[t].w;
      }
      s = blk_red<false>(s);
      float f = 1.f / (s * 4096.f);
      #pragma unroll
      for (int t = 0; t < 4; t++) {
        r[t].x *= f; r[t].y *= f; r[t].z *= f; r[t].w *= f;
        prow[tid + t * 256] = r[t];
        csl[4 * t + 0] += r[t].x; csl[4 * t + 1] += r[t].y;
        csl[4 * t + 2] += r[t].z; csl[4 * t + 3] += r[t].w;
      }
    } else {
      float s = 0.f;
      #pragma unroll
      for (int t = 0; t < 4; t++) {
        r[t].x *= cdiv[4 * t + 0]; r[t].y *= cdiv[4 * t + 1];
        r[t].z *= cdiv[4 * t + 2]; r[t].w *= cdiv[4 * t + 3];
        s += r[t].x + r[t].y + r[t].z + r[t].w;
      }
      s = blk_red<false>(s);
      if (mode == 1) {
        float f = 1.f / (4096.f * s);
        #pragma unroll
        for (int t = 0; t < 4; t++) {
          r[t].x *= f; r[t].y *= f; r[t].z *= f; r[t].w *= f;
          prow[tid + t * 256] = r[t];
          csl[4 * t + 0] += r[t].x; csl[4 * t + 1] += r[t].y;
          csl[4 * t + 2] += r[t].z; csl[4 * t + 3] += r[t].w;
        }
      } else {
        if (tid == 0) rs[row] = s;
        #pragma unroll
        for (int t = 0; t < 4; t++) {
          prow[tid + t * 256] = r[t];
          u16x4 w;
          w[0] = f2bf(r[t].x); w[1] = f2bf(r[t].y);
          w[2] = f2bf(r[t].z); w[3] = f2bf(r[t].w);
          *(u16x4*)&Pb[(size_t)row * 4096 + 4 * (tid + t * 256)] = w;
          csl[4 * t + 0] += r[t].x; csl[4 * t + 1] += r[t].y;
          csl[4 * t + 2] += r[t].z; csl[4 * t + 3] += r[t].w;
        }
      }
    }
  }
  #pragma unroll
  for (int t = 0; t < 4; t++) {
    int j = 4 * (tid + t * 256);
    atomicAdd(&cs_out[j + 0], csl[4 * t + 0]);
    atomicAdd(&cs_out[j + 1], csl[4 * t + 1]);
    atomicAdd(&cs_out[j + 2], csl[4 * t + 2]);
    atomicAdd(&cs_out[j + 3], csl[4 * t + 3]);
  }
}

// mask rowsums (one block per row)
__global__ __launch_bounds__(256)
void rowsum_k(const float* __restrict__ Pm, float* __restrict__ vec)
{
  int i = blockIdx.x, tid = threadIdx.x;
  const float4* prow = (const float4*)(Pm + (size_t)i * kN);
  float s = 0.f;
  #pragma unroll
  for (int t = 0; t < 4; t++) {
    float4 r = prow[tid + t * 256];
    s += r.x + r.y + r.z + r.w;
  }
  s = blk_red<false>(s);
  if (tid == 0) vec[i] = s;
}

__global__ void relu_k(const float* __restrict__ in, float* __restrict__ out, int n)
{
  int i = blockIdx.x * blockDim.x + threadIdx.x;
  if (i < n) out[i] = fmaxf(in[i], 0.f);
}

// XP[i][64+j] = XP[perm[i]][j]
__global__ void gather_k(float* __restrict__ XP, const int* __restrict__ perm)
{
  int gid = blockIdx.x * 256 + threadIdx.x;
  int i = gid >> 6, j = gid & 63;
  XP[(size_t)i * 128 + 64 + j] = XP[(size_t)perm[i] * 128 + j];
}

// per-row squared L2 of [4096][ld], first 64 cols (one wave per row)
__global__ void sqnorm_k(const float* __restrict__ H, int ld, float* __restrict__ outv)
{
  int gid = blockIdx.x * 256 + threadIdx.x;
  int row = gid >> 6, j = gid & 63;
  float v = H[(size_t)row * ld + j];
  float p = wave_red_sum(v * v);
  if (j == 0) outv[row] = p;
}

__global__ void readout_k(const float* __restrict__ vs2, const float* __restrict__ mrs,
                          float* __restrict__ g2)
{
  int q = blockIdx.x, j = threadIdx.x;
  float v = vs2[(size_t)q * 64 + j] / mrs[q >> 1];
  float p = v * v;
  #pragma unroll
  for (int s = 1; s < 64; s <<= 1) p += __shfl_xor(p, s, 64);
  float nrm = sqrtf(p);
  v = v / fmaxf(nrm, 1e-12f);
  g2[(size_t)q * 64 + j] = 1.f / (1.f + expf(-v));
}

__device__ __forceinline__ float bce_term(float x, float y) {
  return fmaxf(x, 0.f) - x * y + log1pf(expf(-fabsf(x)));
}

__global__ void disc_k(const float* __restrict__ G2, const float* __restrict__ W2,
                       const float* __restrict__ lab, const float* __restrict__ bptr,
                       float* __restrict__ acc)
{
  int i = blockIdx.x, j = threadIdx.x;
  float gj  = G2[(size_t)(2 * i) * 64 + j];
  float gaj = G2[(size_t)(2 * i + 1) * 64 + j];
  float hw  = W2[(size_t)(2 * i) * 64 + j];
  float haw = W2[(size_t)(2 * i + 1) * 64 + j];
  float s1 = hw * gj, s2 = haw * gj, s1a = haw * gaj, s2a = hw * gaj;
  #pragma unroll
  for (int s = 1; s < 64; s <<= 1) {
    s1  += __shfl_xor(s1, s, 64);
    s2  += __shfl_xor(s2, s, 64);
    s1a += __shfl_xor(s1a, s, 64);
    s2a += __shfl_xor(s2a, s, 64);
  }
  if (j == 0) {
    float b = bptr[0];
    float y0 = lab[i * 2 + 0], y1 = lab[i * 2 + 1];
    float t = bce_term(s1 + b, y0) + bce_term(s2 + b, y1)
            + bce_term(s1a + b, y0) + bce_term(s2a + b, y1);
    atomicAdd(&acc[SL], t);
  }
}

__global__ __launch_bounds__(256)
void finalize_k(const float* __restrict__ acc, const float* __restrict__ cs,
                float* __restrict__ out)
{
  int tid = threadIdx.x;
  float invm2 = 1.f / (float)kN;
  float t = 0.f;
  for (int j = tid; j < kN; j += 256) {
    float q = cs[j];
    t += q * (logf(q) - invm2);
  }
  t = blk_red<false>(t);
  if (tid == 0) {
    float kld_pq = t * invm2;
    float kld_pp = invm2 * (logf(invm2) - invm2);
    out[0] = acc[SL] / (2.f * (float)kN);
    out[1] = acc[FEAT] / ((float)kN * (float)kIN);
    out[2] = acc[ALN];
    out[3] = (acc[FXA] + acc[FXB]) / ((float)kN * (float)kIN);
    out[4] = sqrtf(acc[SM1]) / (float)kN + sqrtf(acc[SM2]) / (float)kN;
    out[5] = (kld_pq - kld_pp) * (float)kN;
    out[6] = -acc[SPS];
  }
}

// ---------------- host-side dispatch ----------------
static void gemm_launch(hipStream_t st, int TA, int TB, int EPI,
                        const float* A, const float* B, float* C, const float* X,
                        const float* rowdiv, const float* coldiv, float alpha, float* slot,
                        int M, int Ncc, int K, int ldA, int ldB, int ldC, int kchunk)
{
  dim3 grid((Ncc + 63) / 64, M / 64, (K + kchunk - 1) / kchunk);
  dim3 blk(256, 1, 1);
  #define GL(ta, tb, epi) gemm_k<ta, tb, epi><<<grid, blk, 0, st>>>( \
      A, B, C, X, rowdiv, coldiv, alpha, slot, M, Ncc, K, ldA, ldB, ldC, kchunk)
  if      (TA == 0 && TB == 0 && EPI == 0) GL(0, 0, 0);
  else if (TA == 0 && TB == 0 && EPI == 1) GL(0, 0, 1);
  else if (TA == 0 && TB == 1 && EPI == 0) GL(0, 1, 0);
  else if (TA == 0 && TB == 1 && EPI == 3) GL(0, 1, 3);
  #undef GL
}

static void bt_launch(hipStream_t st, int EPI,
                      const unsigned short* A, const unsigned short* Bt,
                      unsigned short* C, const float* X,
                      const float* rowdiv, const float* coldiv, float* slot,
                      int gx, int Nc, int K, int ldX, int sym)
{
  int nwg = (EPI == 2 && sym) ? 528 : gx * 32;
  if (EPI == 0)
    bt_mfma_k<0><<<nwg, 256, 0, st>>>(A, Bt, C, X, rowdiv, coldiv, slot, gx, Nc, K, ldX, sym);
  else
    bt_mfma_k<2><<<nwg, 256, 0, st>>>(A, Bt, C, X, rowdiv, coldiv, slot, gx, Nc, K, ldX, sym);
}

extern "C" void kernel_launch(void* const* d_in, const int* in_sizes, int n_in,
                              void* d_out, int out_size, void* d_ws, size_t ws_size,
                              hipStream_t stream)
{
  (void)in_sizes; (void)n_in; (void)out_size; (void)ws_size;
  const float* feat  = (const float*)d_in[0];
  const float* adjs  = (const float*)d_in[1];
  const float* gmask = (const float*)d_in[2];
  const float* labs  = (const float*)d_in[3];
  const float* dists = (const float*)d_in[4];
  const int*   perms = (const int*)d_in[5];
  const float* encW  = (const float*)d_in[6];
  const float* decW  = (const float*)d_in[7];
  const float* MsW   = (const float*)d_in[8];
  const float* discW = (const float*)d_in[9];
  const float* discb = (const float*)d_in[10];
  float* out = (float*)d_out;

  const size_t SZNN = (size_t)kN * kN;

  char* cur = (char*)d_ws;
  auto alloc = [&](size_t bytes) {
    char* p = cur;
    cur += (bytes + 15) & ~(size_t)15;
    return p;
  };
  float* P            = (float*)alloc(SZNN * 4);
  unsigned short* Pb  = (unsigned short*)alloc(SZNN * 2);
  unsigned short* PbT = (unsigned short*)alloc(SZNN * 2);
  unsigned short* Db  = (unsigned short*)alloc(SZNN * 2);
  unsigned short* Tb  = (unsigned short*)alloc(SZNN * 2);
  unsigned short* ftb = (unsigned short*)alloc((size_t)kINp * kN * 2);
  unsigned short* dWtb= (unsigned short*)alloc((size_t)kINp * kLAT * 2);
  unsigned short* ahb = (unsigned short*)alloc((size_t)kN * kLAT * 2);
  float* XP  = (float*)alloc((size_t)kN * 128 * 4);
  float* HH0 = (float*)alloc((size_t)kN * 128 * 4);
  float* HH1 = (float*)alloc((size_t)kN * 128 * 4);
  float* HR  = (float*)alloc((size_t)kN * 128 * 4);
  float* VS  = (float*)alloc((size_t)kN * 128 * 4);
  float* G2  = (float*)alloc((size_t)kN * 128 * 4);
  float* W2  = (float*)alloc((size_t)kN * 128 * 4);
  float* SM_ = (float*)alloc((size_t)kN * kLAT * 4);
  float* TM_ = (float*)alloc((size_t)kN * kLAT * 4);
  float* ah  = (float*)alloc((size_t)kN * kLAT * 4);
  float* sns = (float*)alloc(kN * 4);
  float* snt = (float*)alloc(kN * 4);
  float* rs  = (float*)alloc(kN * 4);
  float* cs  = (float*)alloc(kN * 4);
  float* csA = (float*)alloc(kN * 4);
  float* csB = (float*)alloc(kN * 4);
  float* mrs = (float*)alloc(kN * 4);
  float* acc = (float*)alloc(NSLOT * 4);

  hipMemsetAsync(acc, 0, NSLOT * sizeof(float), stream);

  // ---------------- per-slice losses ----------------
  for (int k = 0; k < 2; k++) {
    const float* x    = feat  + (size_t)k * kN * kIN;
    const float* adj  = adjs  + (size_t)k * SZNN;
    const float* msk  = gmask + (size_t)k * SZNN;
    const float* lab  = labs  + (size_t)k * kN * 2;
    const int*   perm = perms + (size_t)k * kN;
    const float* eW   = encW  + (size_t)k * kIN * kLAT;
    const float* dW   = decW  + (size_t)k * kLAT * kIN;
    float* HHk = (k == 0) ? HH0 : HH1;

    hipMemsetAsync(XP, 0, (size_t)kN * 128 * 4, stream);
    gemm_launch(stream, 0, 0, 1, x, eW, XP, nullptr, nullptr, nullptr, 1.f, nullptr,
                kN, kLAT, kIN, kIN, kLAT, 128, 192);
    gather_k<<<kN * 64 / 256, 256, 0, stream>>>(XP, perm);
    hipMemsetAsync(HHk, 0, (size_t)kN * 128 * 4, stream);
    gemm_launch(stream, 0, 0, 1, adj, XP, HHk, nullptr, nullptr, nullptr, 1.f, nullptr,
                kN, 128, kN, kN, 128, 128, 256);
    hipMemsetAsync(ah, 0, (size_t)kN * kLAT * 4, stream);
    gemm_launch(stream, 0, 0, 1, adj, HHk, ah, nullptr, nullptr, nullptr, 1.f, nullptr,
                kN, kLAT, kN, kN, 128, kLAT, 128);
    cvt_k<<<(kN * kLAT / 8 + 255) / 256, 256, 0, stream>>>(ah, ahb, kN * kLAT / 8);
    tr_k<<<dim3(kINp / 32, 2), 256, 0, stream>>>(dW, dWtb, kLAT, kIN, kINp);
    bt_launch(stream, 2, ahb, dWtb, nullptr, x, nullptr, nullptr, &acc[FEAT],
              kINp / 128, kIN, kLAT, kIN, 0);
    relu_k<<<kN * 128 / 256, 256, 0, stream>>>(HHk, HR, kN * 128);
    rowsum_k<<<kN, 256, 0, stream>>>(msk, mrs);
    hipMemsetAsync(VS, 0, (size_t)kN * 128 * 4, stream);
    gemm_launch(stream, 0, 0, 1, msk, HR, VS, nullptr, nullptr, nullptr, 1.f, nullptr,
                kN, 128, kN, kN, 128, 128, 256);
    readout_k<<<2 * kN, 64, 0, stream>>>(VS, mrs, G2);
    gemm_launch(stream, 0, 0, 0, HR, discW, W2, nullptr, nullptr, nullptr, 1.f, nullptr,
                2 * kN, kLAT, kLAT, kLAT, kLAT, kLAT, kLAT);
    disc_k<<<kN, 64, 0, stream>>>(G2, W2, lab, discb, acc);
  }

  // ---------------- alignment losses ----------------
  const float* f0 = feat;
  const float* f1 = feat + (size_t)kN * kIN;
  const float* D0 = dists;
  const float* D1 = dists + SZNN;

  gemm_launch(stream, 0, 0, 0, HH0, MsW, SM_, nullptr, nullptr, nullptr, 1.f, nullptr,
              kN, kLAT, kLAT, 128, kLAT, kLAT, kLAT);
  gemm_launch(stream, 0, 0, 0, HH1, MsW, TM_, nullptr, nullptr, nullptr, 1.f, nullptr,
              kN, kLAT, kLAT, 128, kLAT, kLAT, kLAT);
  gemm_launch(stream, 0, 1, 0, SM_, TM_, P, nullptr, nullptr, nullptr, 0.125f, nullptr,
              kN, kN, kLAT, kLAT, kLAT, kN, kLAT);

  // fused sinkhorn: softmax + 3 iters + final marginals + bf16 P, 4 passes
  hipMemsetAsync(csA, 0, kN * 4, stream);
  sink_k<<<512, 256, 0, stream>>>(P, nullptr, nullptr, csA, nullptr, 0);
  hipMemsetAsync(csB, 0, kN * 4, stream);
  sink_k<<<512, 256, 0, stream>>>(P, nullptr, csA, csB, nullptr, 1);
  hipMemsetAsync(csA, 0, kN * 4, stream);
  sink_k<<<512, 256, 0, stream>>>(P, nullptr, csB, csA, nullptr, 1);
  hipMemsetAsync(cs, 0, kN * 4, stream);
  sink_k<<<512, 256, 0, stream>>>(P, Pb, csA, cs, rs, 2);

  tr_k<<<dim3(kN / 32, kN / 32), 256, 0, stream>>>(P, PbT, kN, kN, kN);

  sqnorm_k<<<kN * 64 / 256, 256, 0, stream>>>(HH0, 128, sns);
  sqnorm_k<<<kN * 64 / 256, 256, 0, stream>>>(HH1, 128, snt);
  gemm_launch(stream, 0, 1, 3, HH0, HH1, nullptr, P, sns, snt, 1.f, acc,
              kN, kN, kLAT, 128, 128, kN, kLAT);

  // loss_align_fix
  tr_k<<<dim3(kINp / 32, kN / 32), 256, 0, stream>>>(f1, ftb, kN, kIN, kINp);
  bt_launch(stream, 2, Pb, ftb, nullptr, f0, rs, nullptr, &acc[FXA],
            kINp / 128, kIN, kN, kIN, 0);
  tr_k<<<dim3(kINp / 32, kN / 32), 256, 0, stream>>>(f0, ftb, kN, kIN, kINp);
  bt_launch(stream, 2, PbT, ftb, nullptr, f1, cs, nullptr, &acc[FXB],
            kINp / 128, kIN, kN, kIN, 0);

  // loss_maintain 1
  cvt_k<<<(int)(SZNN / 8 / 256), 256, 0, stream>>>(D1, Db, (int)(SZNN / 8));
  bt_launch(stream, 0, Pb, Db, Tb, nullptr, rs, nullptr, nullptr,
            kN / 128, kN, kN, 0, 0);
  bt_launch(stream, 2, Tb, Pb, nullptr, D0, nullptr, rs, &acc[SM1],
            kN / 128, kN, kN, kN, 1);
  // loss_maintain 2
  cvt_k<<<(int)(SZNN / 8 / 256), 256, 0, stream>>>(D0, Db, (int)(SZNN / 8));
  bt_launch(stream, 0, PbT, Db, Tb, nullptr, cs, nullptr, nullptr,
            kN / 128, kN, kN, 0, 0);
  bt_launch(stream, 2, Tb, PbT, nullptr, D1, nullptr, cs, &acc[SM2],
            kN / 128, kN, kN, kN, 1);

  finalize_k<<<1, 256, 0, stream>>>(acc, cs, out);
}

// Round 5
// 2051.738 us; speedup vs baseline: 5.4294x; 1.2460x over previous
//
#include <hip/hip_runtime.h>
#include <cmath>

// Problem constants
constexpr int kN   = 4096;
constexpr int kIN  = 3000;
constexpr int kINp = 3072;   // kIN padded to 128-multiple
constexpr int kLAT = 64;

enum { SL = 0, FEAT, ALN, FXA, FXB, SM1, SM2, SPS, NSLOT };

typedef __bf16 bf16x8 __attribute__((ext_vector_type(8)));
typedef float f32x4 __attribute__((ext_vector_type(4)));
typedef unsigned short u16x8 __attribute__((ext_vector_type(8)));
typedef unsigned short u16x4 __attribute__((ext_vector_type(4)));

// ---------------- reduction helpers ----------------
template<bool IS_MAX>
__device__ __forceinline__ float blk_red(float v) {
  __shared__ float buf[4];
  #pragma unroll
  for (int s = 32; s > 0; s >>= 1) {
    float o = __shfl_down(v, s, 64);
    v = IS_MAX ? fmaxf(v, o) : (v + o);
  }
  int lane = threadIdx.x & 63, wv = threadIdx.x >> 6, nw = blockDim.x >> 6;
  __syncthreads();
  if (lane == 0) buf[wv] = v;
  __syncthreads();
  float r = buf[0];
  for (int i = 1; i < nw; i++) r = IS_MAX ? fmaxf(r, buf[i]) : (r + buf[i]);
  return r;
}

__device__ __forceinline__ float wave_red_sum(float v) {
  #pragma unroll
  for (int s = 32; s > 0; s >>= 1) v += __shfl_down(v, s, 64);
  return v;
}

// fp32 -> bf16 RNE ; bf16 -> fp32
__device__ __forceinline__ unsigned short f2bf(float f) {
  unsigned u = __builtin_bit_cast(unsigned, f);
  u += 0x7fffu + ((u >> 16) & 1u);
  return (unsigned short)(u >> 16);
}
__device__ __forceinline__ float bf2f(unsigned short h) {
  return __builtin_bit_cast(float, (unsigned)h << 16);
}

// async global->LDS, 16B per lane
__device__ __forceinline__ void gload16(const unsigned short* g, unsigned short* l) {
  __builtin_amdgcn_global_load_lds(
      (const __attribute__((address_space(1))) unsigned int*)g,
      (__attribute__((address_space(3))) unsigned int*)l, 16, 0, 0);
}

// ================== uniform bf16 MFMA GEMM: C = A @ Bt^T ==================
// A: [4096][K] bf16 (ldA=K). Bt: [Ncpad][K] bf16 (ldBt=K). M fixed 4096.
// 128x128 tile, BK=32, 3-deep LDS pipeline (vmcnt(8) steady state).
// EPI 0: Cb[r*4096+c] = bf16(acc / rowdiv[r])
// EPI 1: Cf[r*4096+c] = acc              (fp32 store)
// EPI 2: slot += wgt*sum_{c<Nc} (X - acc/rowdiv[r]/coldiv[c])^2 ; X fp32 (XBF=0) or bf16 (XBF=1)
// EPI 3: align+sparsity: g=acc; p=X(bf16); d2=rowdiv[r]+coldiv[c]-2g;
//        slot[ALN]+=p*sqrt(max(d2,1e-12)); slot[SPS]+=p*log(p+1e-10)
template<int EPI, int XBF>
__global__ __launch_bounds__(256)
void bt_mfma_k(const unsigned short* __restrict__ A, const unsigned short* __restrict__ Bt,
               unsigned short* __restrict__ Cb, float* __restrict__ Cf,
               const void* __restrict__ Xv,
               const float* __restrict__ rowdiv, const float* __restrict__ coldiv,
               float* __restrict__ slot, int gx, int Nc, int K, int ldX, int sym)
{
  __shared__ unsigned short AB[3 * 8192];   // 3 bufs x (A 4096 + B 4096) ushorts = 48 KB

  int orig = blockIdx.x;
  int bx, by;
  if (EPI == 2 && sym) {
    // 528 upper-tri tiles of a 32x32 grid; XCD-chunked bijective (528 = 8*66)
    int x = orig & 7, i = orig >> 3;
    int u = x * 66 + i;
    float disc = 4225.f - 8.f * (float)u;
    by = (int)((65.f - sqrtf(fmaxf(disc, 0.f))) * 0.5f);
    while (by > 0 && 32 * by - by * (by - 1) / 2 > u) by--;
    while (32 * (by + 1) - (by + 1) * by / 2 <= u) by++;
    bx = by + (u - (32 * by - by * (by - 1) / 2));
  } else {
    // strip: XCD x owns rows 4x..4x+3, column-major traversal within strip
    int x = orig & 7, tt = orig >> 3;
    bx = tt >> 2;
    by = x * 4 + (tt & 3);
  }
  const int row0 = by * 128, col0 = bx * 128;

  const int t = threadIdx.x, l = t & 63, wv = t >> 6;
  const int wr = wv >> 1, wc = wv & 1;
  const int lr = l & 15, lkh = (l >> 4) << 3;

  f32x4 acc[4][4];
  #pragma unroll
  for (int i = 0; i < 4; i++)
    #pragma unroll
    for (int j = 0; j < 4; j++) acc[i][j] = (f32x4){0.f, 0.f, 0.f, 0.f};

  const int srow = l >> 2;            // row within a 16-row chunk
  const int sk   = (l & 3) << 3;      // 8 ushorts = 16B
  const unsigned short* Ab = A  + (size_t)(row0 + srow) * K + sk;
  const unsigned short* Bb = Bt + (size_t)(col0 + srow) * K + sk;

  const int NT = K >> 5;

  auto STAGE = [&](int kt, int buf) {
    unsigned short* As = AB + buf * 8192;
    unsigned short* Bs = As + 4096;
    int k0 = kt << 5;
    #pragma unroll
    for (int h2 = 0; h2 < 2; h2++) {
      int c = wv * 2 + h2;            // wave-uniform chunk id 0..7
      gload16(Ab + (size_t)c * 16 * K + k0, As + c * 512);
      gload16(Bb + (size_t)c * 16 * K + k0, Bs + c * 512);
    }
  };

  STAGE(0, 0);
  if (NT > 1) STAGE(1, 1);
  if (NT > 2) STAGE(2, 2);
  int cur = 0;

  for (int kt = 0; kt < NT; ++kt) {
    int ahead = NT - 1 - kt;
    if (ahead >= 2)      { asm volatile("s_waitcnt vmcnt(8)" ::: "memory"); }
    else if (ahead == 1) { asm volatile("s_waitcnt vmcnt(4)" ::: "memory"); }
    else                 { asm volatile("s_waitcnt vmcnt(0)" ::: "memory"); }
    __builtin_amdgcn_sched_barrier(0);
    __builtin_amdgcn_s_barrier();

    const unsigned short* As = AB + cur * 8192;
    const unsigned short* Bs = As + 4096;
    u16x8 af[4], bfv[4];
    #pragma unroll
    for (int mi = 0; mi < 4; mi++)
      af[mi] = *(const u16x8*)&As[(wr * 64 + mi * 16 + lr) * 32 + lkh];
    #pragma unroll
    for (int ni = 0; ni < 4; ni++)
      bfv[ni] = *(const u16x8*)&Bs[(wc * 64 + ni * 16 + lr) * 32 + lkh];
    #pragma unroll
    for (int mi = 0; mi < 4; mi++)
      #pragma unroll
      for (int ni = 0; ni < 4; ni++)
        acc[mi][ni] = __builtin_amdgcn_mfma_f32_16x16x32_bf16(
            __builtin_bit_cast(bf16x8, af[mi]),
            __builtin_bit_cast(bf16x8, bfv[ni]), acc[mi][ni], 0, 0, 0);

    __builtin_amdgcn_s_barrier();     // buf[cur] reads done -> safe to overwrite
    if (kt + 3 < NT) STAGE(kt + 3, cur);
    cur = (cur == 2) ? 0 : cur + 1;
  }

  // C/D mapping: col = lane&15, row = (lane>>4)*4 + reg
  const int lcol = l & 15, lrow = (l >> 4) << 2;
  if (EPI == 0) {
    #pragma unroll
    for (int mi = 0; mi < 4; mi++) {
      int rr = row0 + wr * 64 + mi * 16 + lrow;
      #pragma unroll
      for (int ni = 0; ni < 4; ni++) {
        int cc = col0 + wc * 64 + ni * 16 + lcol;
        #pragma unroll
        for (int r = 0; r < 4; r++) {
          float v = acc[mi][ni][r];
          if (rowdiv) v /= rowdiv[rr + r];
          Cb[(size_t)(rr + r) * 4096 + cc] = f2bf(v);
        }
      }
    }
  } else if (EPI == 1) {
    #pragma unroll
    for (int mi = 0; mi < 4; mi++) {
      int rr = row0 + wr * 64 + mi * 16 + lrow;
      #pragma unroll
      for (int ni = 0; ni < 4; ni++) {
        int cc = col0 + wc * 64 + ni * 16 + lcol;
        #pragma unroll
        for (int r = 0; r < 4; r++)
          Cf[(size_t)(rr + r) * 4096 + cc] = acc[mi][ni][r];
      }
    }
  } else if (EPI == 2) {
    const float* Xf = (const float*)Xv;
    const unsigned short* Xh = (const unsigned short*)Xv;
    float part = 0.f;
    #pragma unroll
    for (int mi = 0; mi < 4; mi++) {
      int rr = row0 + wr * 64 + mi * 16 + lrow;
      #pragma unroll
      for (int ni = 0; ni < 4; ni++) {
        int cc = col0 + wc * 64 + ni * 16 + lcol;
        if (cc < Nc) {
          float cd = coldiv ? coldiv[cc] : 1.f;
          #pragma unroll
          for (int r = 0; r < 4; r++) {
            float v = acc[mi][ni][r];
            if (rowdiv) v /= rowdiv[rr + r];
            v /= cd;
            size_t xi = (size_t)(rr + r) * ldX + cc;
            float xval = XBF ? bf2f(Xh[xi]) : Xf[xi];
            float d = xval - v;
            part = fmaf(d, d, part);
          }
        }
      }
    }
    part = blk_red<false>(part);
    if (t == 0) {
      float wgt = (sym && col0 > row0) ? 2.f : 1.f;
      atomicAdd(slot, part * wgt);
    }
  } else { // EPI 3
    const unsigned short* Ph = (const unsigned short*)Xv;
    float a = 0.f, sp = 0.f;
    #pragma unroll
    for (int mi = 0; mi < 4; mi++) {
      int rr = row0 + wr * 64 + mi * 16 + lrow;
      #pragma unroll
      for (int ni = 0; ni < 4; ni++) {
        int cc = col0 + wc * 64 + ni * 16 + lcol;
        #pragma unroll
        for (int r = 0; r < 4; r++) {
          float g = acc[mi][ni][r];
          float p = bf2f(Ph[(size_t)(rr + r) * ldX + cc]);
          float d2 = rowdiv[rr + r] + coldiv[cc] - 2.f * g;
          a = fmaf(p, sqrtf(fmaxf(d2, 1e-12f)), a);
          sp = fmaf(p, logf(p + 1e-10f), sp);
        }
      }
    }
    a = blk_red<false>(a);
    sp = blk_red<false>(sp);
    if (t == 0) { atomicAdd(&slot[ALN], a); atomicAdd(&slot[SPS], sp); }
  }
}

// ============ narrow split-K bf16 MFMA: C[4096][Nc<=128] += A @ Bt^T ============
// A: [4096][K] bf16. Bt: [128][K] bf16 (rows >= Nc zero-padded). C fp32, pre-zeroed.
// grid = 32 strips x 16 K-chunks; KC = K/16 elems per chunk. 2-deep pipeline.
__global__ __launch_bounds__(256)
void ns_mfma_k(const unsigned short* __restrict__ A, const unsigned short* __restrict__ Bt,
               float* __restrict__ C, int Nc, int K, int KC, int ldC)
{
  __shared__ unsigned short AB[2 * 8192];
  int ks = blockIdx.x & 15, strip = blockIdx.x >> 4;
  const int row0 = strip * 128;
  const int kbase = ks * KC;

  const int t = threadIdx.x, l = t & 63, wv = t >> 6;
  const int wr = wv >> 1, wc = wv & 1;
  const int lr = l & 15, lkh = (l >> 4) << 3;

  f32x4 acc[4][4];
  #pragma unroll
  for (int i = 0; i < 4; i++)
    #pragma unroll
    for (int j = 0; j < 4; j++) acc[i][j] = (f32x4){0.f, 0.f, 0.f, 0.f};

  const int srow = l >> 2;
  const int sk   = (l & 3) << 3;
  const unsigned short* Ab = A  + (size_t)(row0 + srow) * K + kbase + sk;
  const unsigned short* Bb = Bt + (size_t)srow * K + kbase + sk;

  const int NT = KC >> 5;

  auto STAGE = [&](int kt, int buf) {
    unsigned short* As = AB + buf * 8192;
    unsigned short* Bs = As + 4096;
    int k0 = kt << 5;
    #pragma unroll
    for (int h2 = 0; h2 < 2; h2++) {
      int c = wv * 2 + h2;
      gload16(Ab + (size_t)c * 16 * K + k0, As + c * 512);
      gload16(Bb + (size_t)c * 16 * K + k0, Bs + c * 512);
    }
  };

  STAGE(0, 0);
  if (NT > 1) STAGE(1, 1);
  int cur = 0;

  for (int kt = 0; kt < NT; ++kt) {
    if (kt + 1 < NT) { asm volatile("s_waitcnt vmcnt(4)" ::: "memory"); }
    else             { asm volatile("s_waitcnt vmcnt(0)" ::: "memory"); }
    __builtin_amdgcn_sched_barrier(0);
    __builtin_amdgcn_s_barrier();

    const unsigned short* As = AB + cur * 8192;
    const unsigned short* Bs = As + 4096;
    u16x8 af[4], bfv[4];
    #pragma unroll
    for (int mi = 0; mi < 4; mi++)
      af[mi] = *(const u16x8*)&As[(wr * 64 + mi * 16 + lr) * 32 + lkh];
    #pragma unroll
    for (int ni = 0; ni < 4; ni++)
      bfv[ni] = *(const u16x8*)&Bs[(wc * 64 + ni * 16 + lr) * 32 + lkh];
    #pragma unroll
    for (int mi = 0; mi < 4; mi++)
      #pragma unroll
      for (int ni = 0; ni < 4; ni++)
        acc[mi][ni] = __builtin_amdgcn_mfma_f32_16x16x32_bf16(
            __builtin_bit_cast(bf16x8, af[mi]),
            __builtin_bit_cast(bf16x8, bfv[ni]), acc[mi][ni], 0, 0, 0);

    __builtin_amdgcn_s_barrier();
    if (kt + 2 < NT) STAGE(kt + 2, cur);
    cur ^= 1;
  }

  const int lcol = l & 15, lrow = (l >> 4) << 2;
  #pragma unroll
  for (int mi = 0; mi < 4; mi++) {
    int rr = row0 + wr * 64 + mi * 16 + lrow;
    #pragma unroll
    for (int ni = 0; ni < 4; ni++) {
      int cc = wc * 64 + ni * 16 + lcol;
      if (cc < Nc) {
        #pragma unroll
        for (int r = 0; r < 4; r++)
          atomicAdd(&C[(size_t)(rr + r) * ldC + cc], acc[mi][ni][r]);
      }
    }
  }
}

// ---------------- conversion / transpose pre-passes ----------------
__global__ void cvt_k(const float* __restrict__ s, unsigned short* __restrict__ d,
                      int n8, float scale)
{
  int i = blockIdx.x * 256 + threadIdx.x;
  if (i < n8) {
    float4 a = ((const float4*)s)[2 * i], b = ((const float4*)s)[2 * i + 1];
    u16x8 w;
    w[0] = f2bf(a.x * scale); w[1] = f2bf(a.y * scale);
    w[2] = f2bf(a.z * scale); w[3] = f2bf(a.w * scale);
    w[4] = f2bf(b.x * scale); w[5] = f2bf(b.y * scale);
    w[6] = f2bf(b.z * scale); w[7] = f2bf(b.w * scale);
    ((u16x8*)d)[i] = w;
  }
}

// [4096][3000] fp32 -> [4096][3072] bf16 zero-padded. grid 6144 x 256
__global__ void cvt_pad_k(const float* __restrict__ s, unsigned short* __restrict__ d)
{
  int i = blockIdx.x * 256 + threadIdx.x;     // chunk of 8; 4096*384 chunks
  int row = i / 384, c8 = (i - row * 384) * 8;
  u16x8 w = (u16x8)0;
  if (c8 < kIN) {
    const float* sp = s + (size_t)row * kIN + c8;
    float4 a = *(const float4*)sp, b = *(const float4*)(sp + 4);
    w[0] = f2bf(a.x); w[1] = f2bf(a.y); w[2] = f2bf(a.z); w[3] = f2bf(a.w);
    w[4] = f2bf(b.x); w[5] = f2bf(b.y); w[6] = f2bf(b.z); w[7] = f2bf(b.w);
  }
  ((u16x8*)d)[i] = w;
}

// [4096][128] fp32 cols 0..63 -> [4096][64] bf16. grid 128 x 256
__global__ void cvt_cols_k(const float* __restrict__ s, unsigned short* __restrict__ d)
{
  int i = blockIdx.x * 256 + threadIdx.x;     // 4096*8 chunks of 8
  int row = i >> 3, c8 = (i & 7) * 8;
  const float* sp = s + (size_t)row * 128 + c8;
  float4 a = *(const float4*)sp, b = *(const float4*)(sp + 4);
  u16x8 w;
  w[0] = f2bf(a.x); w[1] = f2bf(a.y); w[2] = f2bf(a.z); w[3] = f2bf(a.w);
  w[4] = f2bf(b.x); w[5] = f2bf(b.y); w[6] = f2bf(b.z); w[7] = f2bf(b.w);
  ((u16x8*)d)[i] = w;
}

// transpose+convert: src fp32 [R][C] (ld sld) -> dst bf16 [*][*] (ld dld), optional relu
template<bool RELU>
__global__ void tr_k(const float* __restrict__ src, unsigned short* __restrict__ dst,
                     int R, int C, int sld, int dld)
{
  __shared__ float tile[32][33];
  int c0 = blockIdx.x * 32, r0 = blockIdx.y * 32;
  int tr_ = threadIdx.x >> 3, tc4 = (threadIdx.x & 7) << 2;
  #pragma unroll
  for (int j = 0; j < 4; j++) {
    int r = r0 + tr_, c = c0 + tc4 + j;
    float v = (r < R && c < C) ? src[(size_t)r * sld + c] : 0.f;
    if (RELU) v = fmaxf(v, 0.f);
    tile[tr_][tc4 + j] = v;
  }
  __syncthreads();
  u16x4 wv;
  #pragma unroll
  for (int j = 0; j < 4; j++) wv[j] = f2bf(tile[tc4 + j][tr_]);
  *(u16x4*)&dst[(size_t)(c0 + tr_) * dld + r0 + tc4] = wv;
}

// ---------------- small fp32 GEMM (64-col weight GEMMs only) ----------------
__global__ __launch_bounds__(256)
void gemm_small_k(const float* __restrict__ A, const float* __restrict__ B,
                  float* __restrict__ C, int M, int Nc, int K,
                  int ldA, int ldB, int ldC)
{
  __shared__ float As[16][68];
  __shared__ float Bs[16][68];
  int tid = threadIdx.x;
  int tx = tid & 15, ty = tid >> 4;
  int row0 = blockIdx.y * 64, col0 = blockIdx.x * 64;
  float acc[4][4] = {};

  for (int k0 = 0; k0 < K; k0 += 16) {
    {
      int m = tid >> 2, kk = (tid & 3) << 2;
      const float* ap = A + (size_t)(row0 + m) * ldA + k0 + kk;
      float4 v = *(const float4*)ap;
      As[kk + 0][m] = v.x; As[kk + 1][m] = v.y; As[kk + 2][m] = v.z; As[kk + 3][m] = v.w;
    }
    {
      int kk = tid >> 4, c = (tid & 15) << 2;
      const float* bp = B + (size_t)(k0 + kk) * ldB + col0 + c;
      #pragma unroll
      for (int i = 0; i < 4; i++)
        Bs[kk][c + i] = (col0 + c + i < Nc) ? bp[i] : 0.f;
    }
    __syncthreads();
    #pragma unroll
    for (int kk = 0; kk < 16; kk++) {
      float4 a4 = *(const float4*)&As[kk][ty << 2];
      float4 b4 = *(const float4*)&Bs[kk][tx << 2];
      float av[4] = {a4.x, a4.y, a4.z, a4.w};
      float bv[4] = {b4.x, b4.y, b4.z, b4.w};
      #pragma unroll
      for (int i = 0; i < 4; i++)
        #pragma unroll
        for (int j = 0; j < 4; j++)
          acc[i][j] = fmaf(av[i], bv[j], acc[i][j]);
    }
    __syncthreads();
  }
  #pragma unroll
  for (int i = 0; i < 4; i++) {
    int r = row0 + (ty << 2) + i;
    #pragma unroll
    for (int j = 0; j < 4; j++) {
      int c = col0 + (tx << 2) + j;
      if (c < Nc) C[(size_t)r * ldC + c] = acc[i][j];
    }
  }
}

// ---------------- fused Sinkhorn passes ----------------
__global__ __launch_bounds__(256)
void sink_k(float* __restrict__ P, unsigned short* __restrict__ Pb,
            const float* __restrict__ cs_in, float* __restrict__ cs_out,
            float* __restrict__ rs, int mode)
{
  int tid = threadIdx.x;
  int r0 = blockIdx.x * 8;
  float csl[16] = {};
  float cdiv[16];
  if (mode != 0) {
    #pragma unroll
    for (int t = 0; t < 4; t++) {
      float4 c4 = ((const float4*)cs_in)[tid + t * 256];
      cdiv[4 * t + 0] = 1.f / (4096.f * c4.x);
      cdiv[4 * t + 1] = 1.f / (4096.f * c4.y);
      cdiv[4 * t + 2] = 1.f / (4096.f * c4.z);
      cdiv[4 * t + 3] = 1.f / (4096.f * c4.w);
    }
  }
  for (int rr = 0; rr < 8; rr++) {
    int row = r0 + rr;
    float4* prow = (float4*)(P + (size_t)row * 4096);
    float4 r[4];
    #pragma unroll
    for (int t = 0; t < 4; t++) r[t] = prow[tid + t * 256];

    if (mode == 0) {
      float m = -3.4e38f;
      #pragma unroll
      for (int t = 0; t < 4; t++)
        m = fmaxf(m, fmaxf(fmaxf(r[t].x, r[t].y), fmaxf(r[t].z, r[t].w)));
      m = blk_red<true>(m);
      float s = 0.f;
      #pragma unroll
      for (int t = 0; t < 4; t++) {
        r[t].x = expf(r[t].x - m); r[t].y = expf(r[t].y - m);
        r[t].z = expf(r[t].z - m); r[t].w = expf(r[t].w - m);
        s += r[t].x + r[t].y + r[t].z + r[t].w;
      }
      s = blk_red<false>(s);
      float f = 1.f / (s * 4096.f);
      #pragma unroll
      for (int t = 0; t < 4; t++) {
        r[t].x *= f; r[t].y *= f; r[t].z *= f; r[t].w *= f;
        prow[tid + t * 256] = r[t];
        csl[4 * t + 0] += r[t].x; csl[4 * t + 1] += r[t].y;
        csl[4 * t + 2] += r[t].z; csl[4 * t + 3] += r[t].w;
      }
    } else {
      float s = 0.f;
      #pragma unroll
      for (int t = 0; t < 4; t++) {
        r[t].x *= cdiv[4 * t + 0]; r[t].y *= cdiv[4 * t + 1];
        r[t].z *= cdiv[4 * t + 2]; r[t].w *= cdiv[4 * t + 3];
        s += r[t].x + r[t].y + r[t].z + r[t].w;
      }
      s = blk_red<false>(s);
      if (mode == 1) {
        float f = 1.f / (4096.f * s);
        #pragma unroll
        for (int t = 0; t < 4; t++) {
          r[t].x *= f; r[t].y *= f; r[t].z *= f; r[t].w *= f;
          prow[tid + t * 256] = r[t];
          csl[4 * t + 0] += r[t].x; csl[4 * t + 1] += r[t].y;
          csl[4 * t + 2] += r[t].z; csl[4 * t + 3] += r[t].w;
        }
      } else {
        if (tid == 0) rs[row] = s;
        #pragma unroll
        for (int t = 0; t < 4; t++) {
          prow[tid + t * 256] = r[t];
          u16x4 w;
          w[0] = f2bf(r[t].x); w[1] = f2bf(r[t].y);
          w[2] = f2bf(r[t].z); w[3] = f2bf(r[t].w);
          *(u16x4*)&Pb[(size_t)row * 4096 + 4 * (tid + t * 256)] = w;
          csl[4 * t + 0] += r[t].x; csl[4 * t + 1] += r[t].y;
          csl[4 * t + 2] += r[t].z; csl[4 * t + 3] += r[t].w;
        }
      }
    }
  }
  #pragma unroll
  for (int t = 0; t < 4; t++) {
    int j = 4 * (tid + t * 256);
    atomicAdd(&cs_out[j + 0], csl[4 * t + 0]);
    atomicAdd(&cs_out[j + 1], csl[4 * t + 1]);
    atomicAdd(&cs_out[j + 2], csl[4 * t + 2]);
    atomicAdd(&cs_out[j + 3], csl[4 * t + 3]);
  }
}

__global__ __launch_bounds__(256)
void rowsum_k(const float* __restrict__ Pm, float* __restrict__ vec)
{
  int i = blockIdx.x, tid = threadIdx.x;
  const float4* prow = (const float4*)(Pm + (size_t)i * kN);
  float s = 0.f;
  #pragma unroll
  for (int t = 0; t < 4; t++) {
    float4 r = prow[tid + t * 256];
    s += r.x + r.y + r.z + r.w;
  }
  s = blk_red<false>(s);
  if (tid == 0) vec[i] = s;
}

__global__ void relu_k(const float* __restrict__ in, float* __restrict__ out, int n)
{
  int i = blockIdx.x * blockDim.x + threadIdx.x;
  if (i < n) out[i] = fmaxf(in[i], 0.f);
}

__global__ void gather_k(float* __restrict__ XP, const int* __restrict__ perm)
{
  int gid = blockIdx.x * 256 + threadIdx.x;
  int i = gid >> 6, j = gid & 63;
  XP[(size_t)i * 128 + 64 + j] = XP[(size_t)perm[i] * 128 + j];
}

__global__ void sqnorm_k(const float* __restrict__ H, int ld, float* __restrict__ outv)
{
  int gid = blockIdx.x * 256 + threadIdx.x;
  int row = gid >> 6, j = gid & 63;
  float v = H[(size_t)row * ld + j];
  float p = wave_red_sum(v * v);
  if (j == 0) outv[row] = p;
}

__global__ void readout_k(const float* __restrict__ vs2, const float* __restrict__ mrs,
                          float* __restrict__ g2)
{
  int q = blockIdx.x, j = threadIdx.x;
  float v = vs2[(size_t)q * 64 + j] / mrs[q >> 1];
  float p = v * v;
  #pragma unroll
  for (int s = 1; s < 64; s <<= 1) p += __shfl_xor(p, s, 64);
  float nrm = sqrtf(p);
  v = v / fmaxf(nrm, 1e-12f);
  g2[(size_t)q * 64 + j] = 1.f / (1.f + expf(-v));
}

__device__ __forceinline__ float bce_term(float x, float y) {
  return fmaxf(x, 0.f) - x * y + log1pf(expf(-fabsf(x)));
}

__global__ void disc_k(const float* __restrict__ G2, const float* __restrict__ W2,
                       const float* __restrict__ lab, const float* __restrict__ bptr,
                       float* __restrict__ acc)
{
  int i = blockIdx.x, j = threadIdx.x;
  float gj  = G2[(size_t)(2 * i) * 64 + j];
  float gaj = G2[(size_t)(2 * i + 1) * 64 + j];
  float hw  = W2[(size_t)(2 * i) * 64 + j];
  float haw = W2[(size_t)(2 * i + 1) * 64 + j];
  float s1 = hw * gj, s2 = haw * gj, s1a = haw * gaj, s2a = hw * gaj;
  #pragma unroll
  for (int s = 1; s < 64; s <<= 1) {
    s1  += __shfl_xor(s1, s, 64);
    s2  += __shfl_xor(s2, s, 64);
    s1a += __shfl_xor(s1a, s, 64);
    s2a += __shfl_xor(s2a, s, 64);
  }
  if (j == 0) {
    float b = bptr[0];
    float y0 = lab[i * 2 + 0], y1 = lab[i * 2 + 1];
    float t = bce_term(s1 + b, y0) + bce_term(s2 + b, y1)
            + bce_term(s1a + b, y0) + bce_term(s2a + b, y1);
    atomicAdd(&acc[SL], t);
  }
}

__global__ __launch_bounds__(256)
void finalize_k(const float* __restrict__ acc, const float* __restrict__ cs,
                float* __restrict__ out)
{
  int tid = threadIdx.x;
  float invm2 = 1.f / (float)kN;
  float t = 0.f;
  for (int j = tid; j < kN; j += 256) {
    float q = cs[j];
    t += q * (logf(q) - invm2);
  }
  t = blk_red<false>(t);
  if (tid == 0) {
    float kld_pq = t * invm2;
    float kld_pp = invm2 * (logf(invm2) - invm2);
    out[0] = acc[SL] / (2.f * (float)kN);
    out[1] = acc[FEAT] / ((float)kN * (float)kIN);
    out[2] = acc[ALN];
    out[3] = (acc[FXA] + acc[FXB]) / ((float)kN * (float)kIN);
    out[4] = sqrtf(acc[SM1]) / (float)kN + sqrtf(acc[SM2]) / (float)kN;
    out[5] = (kld_pq - kld_pp) * (float)kN;
    out[6] = -acc[SPS];
  }
}

extern "C" void kernel_launch(void* const* d_in, const int* in_sizes, int n_in,
                              void* d_out, int out_size, void* d_ws, size_t ws_size,
                              hipStream_t stream)
{
  (void)in_sizes; (void)n_in; (void)out_size; (void)ws_size;
  const float* feat  = (const float*)d_in[0];
  const float* adjs  = (const float*)d_in[1];
  const float* gmask = (const float*)d_in[2];
  const float* labs  = (const float*)d_in[3];
  const float* dists = (const float*)d_in[4];
  const int*   perms = (const int*)d_in[5];
  const float* encW  = (const float*)d_in[6];
  const float* decW  = (const float*)d_in[7];
  const float* MsW   = (const float*)d_in[8];
  const float* discW = (const float*)d_in[9];
  const float* discb = (const float*)d_in[10];
  float* out = (float*)d_out;

  const size_t SZNN = (size_t)kN * kN;

  char* cur = (char*)d_ws;
  auto alloc = [&](size_t bytes) {
    char* p = cur;
    cur += (bytes + 255) & ~(size_t)255;
    return p;
  };
  float* P            = (float*)alloc(SZNN * 4);          // fp32 P; later reused for Tb
  unsigned short* Pb  = (unsigned short*)alloc(SZNN * 2);
  unsigned short* PbT = (unsigned short*)alloc(SZNN * 2);
  unsigned short* Db  = (unsigned short*)alloc(SZNN * 2);
  unsigned short* ajb = (unsigned short*)alloc(SZNN * 2); // adj/msk bf16; later reused for ftb
  unsigned short* xb  = (unsigned short*)alloc((size_t)kN * kINp * 2);
  unsigned short* dWtb= (unsigned short*)alloc((size_t)kINp * kLAT * 2);
  unsigned short* ahb = (unsigned short*)alloc((size_t)kN * kLAT * 2);
  unsigned short* encWtp = (unsigned short*)alloc((size_t)128 * kINp * 2);
  unsigned short* XPt = (unsigned short*)alloc((size_t)128 * kN * 2);
  unsigned short* hbTp= (unsigned short*)alloc((size_t)128 * kN * 2);
  unsigned short* HRt = (unsigned short*)alloc((size_t)128 * kN * 2);
  unsigned short* smb = (unsigned short*)alloc((size_t)kN * kLAT * 2);
  unsigned short* tmb = (unsigned short*)alloc((size_t)kN * kLAT * 2);
  unsigned short* h0b = (unsigned short*)alloc((size_t)kN * kLAT * 2);
  unsigned short* h1b = (unsigned short*)alloc((size_t)kN * kLAT * 2);
  float* XP  = (float*)alloc((size_t)kN * 128 * 4);
  float* HH0 = (float*)alloc((size_t)kN * 128 * 4);
  float* HH1 = (float*)alloc((size_t)kN * 128 * 4);
  float* HR  = (float*)alloc((size_t)kN * 128 * 4);
  float* VS  = (float*)alloc((size_t)kN * 128 * 4);
  float* G2  = (float*)alloc((size_t)kN * 128 * 4);
  float* W2  = (float*)alloc((size_t)kN * 128 * 4);
  float* SM_ = (float*)alloc((size_t)kN * kLAT * 4);
  float* TM_ = (float*)alloc((size_t)kN * kLAT * 4);
  float* ah  = (float*)alloc((size_t)kN * kLAT * 4);
  float* sns = (float*)alloc(kN * 4);
  float* snt = (float*)alloc(kN * 4);
  float* rs  = (float*)alloc(kN * 4);
  float* cs  = (float*)alloc(kN * 4);
  float* csA = (float*)alloc(kN * 4);
  float* csB = (float*)alloc(kN * 4);
  float* mrs = (float*)alloc(kN * 4);
  float* acc = (float*)alloc(NSLOT * 4);

  unsigned short* Tb  = (unsigned short*)P;     // alias: fp32 P dead before Tb written
  unsigned short* ftb = ajb;                    // alias: adj/msk bf16 dead after slices

  hipMemsetAsync(acc, 0, NSLOT * sizeof(float), stream);

  // ---------------- per-slice losses ----------------
  for (int k = 0; k < 2; k++) {
    const float* x    = feat  + (size_t)k * kN * kIN;
    const float* adj  = adjs  + (size_t)k * SZNN;
    const float* msk  = gmask + (size_t)k * SZNN;
    const float* lab  = labs  + (size_t)k * kN * 2;
    const int*   perm = perms + (size_t)k * kN;
    const float* eW   = encW  + (size_t)k * kIN * kLAT;
    const float* dW   = decW  + (size_t)k * kLAT * kIN;
    float* HHk = (k == 0) ? HH0 : HH1;

    // xb = bf16(x) padded to 3072 cols
    cvt_pad_k<<<6144, 256, 0, stream>>>(x, xb);
    // encWtp rows 0..63 = encW^T (padded); rows 64..127 zero
    hipMemsetAsync(encWtp, 0, (size_t)128 * kINp * 2, stream);
    tr_k<false><<<dim3(2, (kIN + 31) / 32), 256, 0, stream>>>(eW, encWtp, kIN, kLAT, kLAT, kINp);
    // XP cols 0..63 = x @ encW (ns MFMA, split-K 16)
    hipMemsetAsync(XP, 0, (size_t)kN * 128 * 4, stream);
    ns_mfma_k<<<512, 256, 0, stream>>>(xb, encWtp, XP, kLAT, kINp, kINp / 16, 128);
    // XP cols 64..127 = xe[perm]
    gather_k<<<kN * 64 / 256, 256, 0, stream>>>(XP, perm);
    // XPt = bf16(XP^T) [128][4096]
    tr_k<false><<<dim3(4, 128), 256, 0, stream>>>(XP, XPt, kN, 128, 128, kN);
    // ajb = bf16(adj)
    cvt_k<<<(int)(SZNN / 8 / 256), 256, 0, stream>>>(adj, ajb, (int)(SZNN / 8), 1.f);
    // HH = adj @ [xe|xea]
    hipMemsetAsync(HHk, 0, (size_t)kN * 128 * 4, stream);
    ns_mfma_k<<<512, 256, 0, stream>>>(ajb, XPt, HHk, 128, kN, kN / 16, 128);
    // hbTp rows 0..63 = bf16(h^T); rows 64..127 zero
    hipMemsetAsync(hbTp, 0, (size_t)128 * kN * 2, stream);
    tr_k<false><<<dim3(2, 128), 256, 0, stream>>>(HHk, hbTp, kN, kLAT, 128, kN);
    // ah = adj @ h
    hipMemsetAsync(ah, 0, (size_t)kN * kLAT * 4, stream);
    ns_mfma_k<<<512, 256, 0, stream>>>(ajb, hbTp, ah, kLAT, kN, kN / 16, kLAT);
    // FEAT: sum((x - ah@decW)^2), X read as bf16 xb
    cvt_k<<<128, 256, 0, stream>>>(ah, ahb, kN * kLAT / 8, 1.f);
    tr_k<false><<<dim3(kINp / 32, 2), 256, 0, stream>>>(dW, dWtb, kLAT, kIN, kIN, kLAT);
    bt_mfma_k<2, 1><<<(kINp / 128) * 32, 256, 0, stream>>>(
        ahb, dWtb, nullptr, nullptr, xb, nullptr, nullptr, &acc[FEAT],
        kINp / 128, kIN, kLAT, kINp, 0);
    // HR fp32 (for disc path) + HRt bf16 (for VS GEMM)
    relu_k<<<kN * 128 / 256, 256, 0, stream>>>(HHk, HR, kN * 128);
    tr_k<true><<<dim3(4, 128), 256, 0, stream>>>(HHk, HRt, kN, 128, 128, kN);
    // mskb (reuse ajb)
    cvt_k<<<(int)(SZNN / 8 / 256), 256, 0, stream>>>(msk, ajb, (int)(SZNN / 8), 1.f);
    // VS = msk @ relu(HH)
    hipMemsetAsync(VS, 0, (size_t)kN * 128 * 4, stream);
    ns_mfma_k<<<512, 256, 0, stream>>>(ajb, HRt, VS, 128, kN, kN / 16, 128);
    rowsum_k<<<kN, 256, 0, stream>>>(msk, mrs);
    readout_k<<<2 * kN, 64, 0, stream>>>(VS, mrs, G2);
    // W2 = HR(view [8192][64]) @ discW   (small fp32 GEMM)
    gemm_small_k<<<dim3(1, 128), 256, 0, stream>>>(HR, discW, W2, 2 * kN, kLAT, kLAT,
                                                   kLAT, kLAT, kLAT);
    disc_k<<<kN, 64, 0, stream>>>(G2, W2, lab, discb, acc);
  }

  // ---------------- alignment losses ----------------
  const float* f0 = feat;
  const float* f1 = feat + (size_t)kN * kIN;
  const float* D0 = dists;
  const float* D1 = dists + SZNN;

  // srcM/tgtM = h @ M (small fp32), then bf16 with 1/8 folded into smb
  gemm_small_k<<<dim3(1, 64), 256, 0, stream>>>(HH0, MsW, SM_, kN, kLAT, kLAT, 128, kLAT, kLAT);
  gemm_small_k<<<dim3(1, 64), 256, 0, stream>>>(HH1, MsW, TM_, kN, kLAT, kLAT, 128, kLAT, kLAT);
  cvt_k<<<128, 256, 0, stream>>>(SM_, smb, kN * kLAT / 8, 0.125f);
  cvt_k<<<128, 256, 0, stream>>>(TM_, tmb, kN * kLAT / 8, 1.f);
  // P = srcM @ tgtM^T / 8  (MFMA, fp32 store)
  bt_mfma_k<1, 0><<<1024, 256, 0, stream>>>(smb, tmb, nullptr, P, nullptr, nullptr, nullptr,
                                            nullptr, 32, kN, kLAT, 0, 0);

  // fused sinkhorn: softmax + 3 iters + final marginals + bf16 P, 4 passes
  hipMemsetAsync(csA, 0, kN * 4, stream);
  sink_k<<<512, 256, 0, stream>>>(P, nullptr, nullptr, csA, nullptr, 0);
  hipMemsetAsync(csB, 0, kN * 4, stream);
  sink_k<<<512, 256, 0, stream>>>(P, nullptr, csA, csB, nullptr, 1);
  hipMemsetAsync(csA, 0, kN * 4, stream);
  sink_k<<<512, 256, 0, stream>>>(P, nullptr, csB, csA, nullptr, 1);
  hipMemsetAsync(cs, 0, kN * 4, stream);
  sink_k<<<512, 256, 0, stream>>>(P, Pb, csA, cs, rs, 2);

  // PbT = bf16(P^T) — last read of fp32 P
  tr_k<false><<<dim3(kN / 32, kN / 32), 256, 0, stream>>>(P, PbT, kN, kN, kN, kN);

  // align + sparsity: h0@h1^T MFMA with EPI3 epilogue (P read as bf16 Pb)
  cvt_cols_k<<<128, 256, 0, stream>>>(HH0, h0b);
  cvt_cols_k<<<128, 256, 0, stream>>>(HH1, h1b);
  sqnorm_k<<<kN * 64 / 256, 256, 0, stream>>>(HH0, 128, sns);
  sqnorm_k<<<kN * 64 / 256, 256, 0, stream>>>(HH1, 128, snt);
  bt_mfma_k<3, 1><<<1024, 256, 0, stream>>>(h0b, h1b, nullptr, nullptr, Pb, sns, snt, acc,
                                            32, kN, kLAT, kN, 0);

  // loss_align_fix (ftb aliases ajb)
  tr_k<false><<<dim3(kINp / 32, kN / 32), 256, 0, stream>>>(f1, ftb, kN, kIN, kIN, kN);
  bt_mfma_k<2, 0><<<(kINp / 128) * 32, 256, 0, stream>>>(
      Pb, ftb, nullptr, nullptr, f0, rs, nullptr, &acc[FXA], kINp / 128, kIN, kN, kIN, 0);
  tr_k<false><<<dim3(kINp / 32, kN / 32), 256, 0, stream>>>(f0, ftb, kN, kIN, kIN, kN);
  bt_mfma_k<2, 0><<<(kINp / 128) * 32, 256, 0, stream>>>(
      PbT, ftb, nullptr, nullptr, f1, cs, nullptr, &acc[FXB], kINp / 128, kIN, kN, kIN, 0);

  // loss_maintain 1: Tb = (P@D1)/rs ; SM1 = sum((D0 - (Tb@P^T)/rs)^2) sym
  cvt_k<<<(int)(SZNN / 8 / 256), 256, 0, stream>>>(D1, Db, (int)(SZNN / 8), 1.f);
  bt_mfma_k<0, 0><<<1024, 256, 0, stream>>>(Pb, Db, Tb, nullptr, nullptr, rs, nullptr,
                                            nullptr, 32, kN, kN, 0, 0);
  bt_mfma_k<2, 0><<<528, 256, 0, stream>>>(Tb, Pb, nullptr, nullptr, D0, nullptr, rs,
                                           &acc[SM1], 32, kN, kN, kN, 1);
  // loss_maintain 2: Tb = (P^T@D0)/cs ; SM2 = sum((D1 - (Tb@P)/cs)^2) sym
  cvt_k<<<(int)(SZNN / 8 / 256), 256, 0, stream>>>(D0, Db, (int)(SZNN / 8), 1.f);
  bt_mfma_k<0, 0><<<1024, 256, 0, stream>>>(PbT, Db, Tb, nullptr, nullptr, cs, nullptr,
                                            nullptr, 32, kN, kN, 0, 0);
  bt_mfma_k<2, 0><<<528, 256, 0, stream>>>(Tb, PbT, nullptr, nullptr, D1, nullptr, cs,
                                           &acc[SM2], 32, kN, kN, kN, 1);

  finalize_k<<<1, 256, 0, stream>>>(acc, cs, out);
}